// Round 6
// baseline (705.276 us; speedup 1.0000x reference)
//
#include <hip/hip_runtime.h>
#include <hip/hip_bf16.h>

typedef unsigned short ushort_t;
typedef __attribute__((ext_vector_type(8))) short short8;
typedef __attribute__((ext_vector_type(4))) float f32x4;

#define DI __device__ __forceinline__

DI float b2f(unsigned int u16) {
  union { unsigned int i; float f; } v;
  v.i = u16 << 16;
  return v.f;
}
DI ushort_t f2b(float f) {
  union { float f; unsigned int u; } v; v.f = f;
  unsigned int r = v.u + 0x7FFFu + ((v.u >> 16) & 1u);
  return (ushort_t)(r >> 16);
}

// async global->LDS 16B copy: LDS dest is wave-uniform base + lane*16
DI void gl_lds16(const ushort_t* g, ushort_t* l) {
  __builtin_amdgcn_global_load_lds(
      (const __attribute__((address_space(1))) unsigned int*)g,
      (__attribute__((address_space(3))) unsigned int*)l, 16, 0, 0);
}

// ---------------------------------------------------------------------------
// Fused: GroupNorm partial stats (blocks 0..2559) + weight bf16 cvt (2560..3583)
// ---------------------------------------------------------------------------
__global__ __launch_bounds__(256) void fused_pre_kernel(
    const float* __restrict__ video, const float* __restrict__ audio,
    float* __restrict__ part,
    const float* __restrict__ w0, const float* __restrict__ w1,
    const float* __restrict__ w2, const float* __restrict__ w3,
    ushort_t* __restrict__ o0, ushort_t* __restrict__ o1,
    ushort_t* __restrict__ o2, ushort_t* __restrict__ o3) {
  const int bid = blockIdx.x;
  const int tid = threadIdx.x;
  __shared__ float red[8];
  if (bid < 2560) {
    float s = 0.f, ss = 0.f;
    if (bid < 2048) {
      int bg = bid >> 4, f = bid & 15;
      int b = bg >> 5, g = bg & 31;
      const float* base = video + ((size_t)((b * 16 + f) * 768 + g * 24)) * 256 + tid;
#pragma unroll
      for (int cl = 0; cl < 24; ++cl) {
        float v = base[cl * 256];
        s += v; ss += v * v;
      }
    } else {
      int a = bid - 2048;
      int bg = a >> 2, p = a & 3;
      int b = bg >> 5, g = bg & 31;
      const float* base = audio + ((size_t)(b * 768 + g * 24)) * 1024 + p * 256 + tid;
#pragma unroll
      for (int cl = 0; cl < 24; ++cl) {
        float v = base[cl * 1024];
        s += v; ss += v * v;
      }
    }
    for (int off = 32; off > 0; off >>= 1) { s += __shfl_down(s, off, 64); ss += __shfl_down(ss, off, 64); }
    int wv = tid >> 6, ln = tid & 63;
    if (ln == 0) { red[wv * 2] = s; red[wv * 2 + 1] = ss; }
    __syncthreads();
    if (tid == 0) {
      part[bid * 2] = red[0] + red[2] + red[4] + red[6];
      part[bid * 2 + 1] = red[1] + red[3] + red[5] + red[7];
    }
  } else {
    const int n1 = 2304 * 768, n3 = 768 * 768;
    const int total = 2 * n1 + 2 * n3;
    int wb = bid - 2560;
    for (int i = wb * 256 + tid; i < total; i += 1024 * 256) {
      if (i < n1) o0[i] = f2b(w0[i]);
      else if (i < 2 * n1) o1[i - n1] = f2b(w1[i - n1]);
      else if (i < 2 * n1 + n3) o2[i - 2 * n1] = f2b(w2[i - 2 * n1]);
      else o3[i - 2 * n1 - n3] = f2b(w3[i - 2 * n1 - n3]);
    }
  }
}

// ---------------------------------------------------------------------------
// Fused normalize (gn_final folded in: per-block channel stats from `part`).
// Blocks 0..1535: video -> Xv[n][c]; 1536..1919: audio -> Xa[n][c].
// ---------------------------------------------------------------------------
__global__ __launch_bounds__(256) void norm_fused_kernel(
    const float* __restrict__ video, const float* __restrict__ audio,
    const float* __restrict__ part,
    const float* __restrict__ vsc, const float* __restrict__ vbi,
    const float* __restrict__ asc, const float* __restrict__ abi,
    ushort_t* __restrict__ Xv, ushort_t* __restrict__ Xa) {
  __shared__ float T[32][257];
  __shared__ float shm[32], shr[32];
  const int bx = blockIdx.x;
  const int tid = threadIdx.x;
  if (bx < 1536) {
    const int bf = bx / 24, ct = bx % 24;
    const int b = bf >> 4, f = bf & 15;
    const int c0 = ct * 32;
    if (tid < 32) {
      int c = c0 + tid, g = c / 24;
      float s = 0.f, ss = 0.f;
#pragma unroll
      for (int i = 0; i < 16; ++i) {
        s += part[((b * 32 + g) * 16 + i) * 2];
        ss += part[((b * 32 + g) * 16 + i) * 2 + 1];
      }
      const float N = 24.f * 4096.f;
      float m = s / N;
      shm[tid] = m;
      shr[tid] = rsqrtf(ss / N - m * m + 1e-5f);
    }
    __syncthreads();
    for (int i = 0; i < 32; ++i) {
      int c = c0 + i;
      float v = video[((size_t)((b * 16 + f) * 768 + c)) * 256 + tid];
      T[i][tid] = (v - shm[i]) * shr[i] * vsc[c] + vbi[c];
    }
    __syncthreads();
    for (int i = 0; i < 32; ++i) {
      int id = i * 256 + tid;
      int c = id & 31, hw = id >> 5;
      Xv[((size_t)(b * 4096 + f * 256 + hw)) * 768 + c0 + c] = f2b(T[c][hw]);
    }
  } else {
    const int ax = bx - 1536;
    const int bt = ax / 24, ct = ax % 24;
    const int b = bt >> 2, t0 = (bt & 3) * 256;
    const int c0 = ct * 32;
    if (tid < 32) {
      int c = c0 + tid, g = c / 24;
      float s = 0.f, ss = 0.f;
#pragma unroll
      for (int i = 0; i < 4; ++i) {
        s += part[(2048 + (b * 32 + g) * 4 + i) * 2];
        ss += part[(2048 + (b * 32 + g) * 4 + i) * 2 + 1];
      }
      const float N = 24.f * 1024.f;
      float m = s / N;
      shm[tid] = m;
      shr[tid] = rsqrtf(ss / N - m * m + 1e-5f);
    }
    __syncthreads();
    for (int i = 0; i < 32; ++i) {
      int c = c0 + i;
      float v = audio[((size_t)(b * 768 + c)) * 1024 + t0 + tid];
      T[i][tid] = (v - shm[i]) * shr[i] * asc[c] + abi[c];
    }
    __syncthreads();
    for (int i = 0; i < 32; ++i) {
      int id = i * 256 + tid;
      int c = id & 31, tt = id >> 5;
      Xa[((size_t)(b * 1024 + t0 + tt)) * 768 + c0 + c] = f2b(T[c][tt]);
    }
  }
}

// ---------------------------------------------------------------------------
// Fused QKV GEMM (video blocks 0..2303, audio 2304..2879).
// 128x128 tile, 2-phase dbuf gl_lds16 staging, XOR chunk swizzle both sides,
// segment-local XCD bijective block swizzle. Q section pre-scaled by 0.125.
// ---------------------------------------------------------------------------
__global__ __launch_bounds__(256) void qkv_fused_kernel(
    const ushort_t* __restrict__ Xv, const ushort_t* __restrict__ Xa,
    const ushort_t* __restrict__ Wqv, const ushort_t* __restrict__ Wqa,
    const float* __restrict__ vqkv_b, const float* __restrict__ aqkv_b,
    ushort_t* __restrict__ Qv, ushort_t* __restrict__ Kv, ushort_t* __restrict__ Vv,
    ushort_t* __restrict__ Qa, ushort_t* __restrict__ Ka, ushort_t* __restrict__ Va) {
  __shared__ ushort_t sm[32768];  // 64 KiB dbuf
  const int bid = blockIdx.x;
  const int tid = threadIdx.x;
  const int lane = tid & 63, wave = tid >> 6;
  const int quad = lane >> 4, l16 = lane & 15;

  const bool isv = bid < 2304;
  const int lb = isv ? bid : bid - 2304;
  const int nwg = isv ? 2304 : 576;
  const ushort_t* A = isv ? Xv : Xa;
  const ushort_t* W = isv ? Wqv : Wqa;
  const float* bias = isv ? vqkv_b : aqkv_b;
  ushort_t* pQ = isv ? Qv : Qa;
  ushort_t* pK = isv ? Kv : Ka;
  ushort_t* pV = isv ? Vv : Va;
  const int M = isv ? 16384 : 4096;

  const int lid = (lb & 7) * (nwg >> 3) + (lb >> 3);
  const int n0 = (lid % 18) * 128, m0 = (lid / 18) * 128;
  const int wm = (wave & 1) * 64, wn = (wave >> 1) * 64;

  const int srow = wave * 32 + (lane >> 3);
  const int sq = ((lane & 7) ^ (lane >> 3)) * 8;
  const ushort_t* gA = A + (size_t)(m0 + srow) * 768 + sq;
  const ushort_t* gB = W + (size_t)(n0 + srow) * 768 + sq;

  f32x4 acc[4][4];
#pragma unroll
  for (int i = 0; i < 4; ++i)
#pragma unroll
    for (int j = 0; j < 4; ++j) acc[i][j] = (f32x4){0.f, 0.f, 0.f, 0.f};

  auto stage = [&](int kc, int cur) {
    ushort_t* lA = sm + cur * 8192 + wave * 2048;
    ushort_t* lB = sm + 16384 + cur * 8192 + wave * 2048;
#pragma unroll
    for (int i = 0; i < 4; ++i) {
      gl_lds16(gA + (size_t)i * 8 * 768 + kc, lA + i * 512);
      gl_lds16(gB + (size_t)i * 8 * 768 + kc, lB + i * 512);
    }
  };

  stage(0, 0);
  __syncthreads();
  int cur = 0;
  for (int t = 0; t < 12; ++t) {
    if (t < 11) stage((t + 1) * 64, cur ^ 1);
    const ushort_t* cA = sm + cur * 8192;
    const ushort_t* cB = sm + 16384 + cur * 8192;
#pragma unroll
    for (int ks = 0; ks < 2; ++ks) {
      short8 av[4], bv[4];
#pragma unroll
      for (int im = 0; im < 4; ++im) {
        int rr = wm + im * 16 + l16;
        av[im] = *reinterpret_cast<const short8*>(
            cA + rr * 64 + (((ks * 4 + quad) ^ (rr & 7)) * 8));
      }
#pragma unroll
      for (int in = 0; in < 4; ++in) {
        int rr = wn + in * 16 + l16;
        bv[in] = *reinterpret_cast<const short8*>(
            cB + rr * 64 + (((ks * 4 + quad) ^ (rr & 7)) * 8));
      }
#pragma unroll
      for (int im = 0; im < 4; ++im)
#pragma unroll
        for (int in = 0; in < 4; ++in)
          acc[im][in] = __builtin_amdgcn_mfma_f32_16x16x32_bf16(av[im], bv[in], acc[im][in], 0, 0, 0);
    }
    __syncthreads();
    cur ^= 1;
  }

  ushort_t* sC = sm;  // epilogue scratch [128][136] bf16
  const int section = n0 / 768;  // 0=Q 1=K 2=V
  const int obase = n0 - section * 768;
  if (section < 2) {
    const float qs = (section == 0) ? 0.125f : 1.0f;  // fold qk scale into Q
#pragma unroll
    for (int in = 0; in < 4; ++in) {
      int ol = wn + in * 16 + l16;
      float bv_ = bias[n0 + ol];
#pragma unroll
      for (int im = 0; im < 4; ++im)
#pragma unroll
        for (int r = 0; r < 4; ++r) {
          int row = wm + im * 16 + quad * 4 + r;
          sC[row * 136 + ol] = f2b((acc[im][in][r] + bv_) * qs);
        }
    }
    __syncthreads();
    ushort_t* dst = (section == 0) ? pQ : pK;
#pragma unroll
    for (int i = 0; i < 8; ++i) {
      int cid = i * 256 + tid;
      int row = cid >> 4, ch = cid & 15;
      *reinterpret_cast<uint4*>(dst + (size_t)(m0 + row) * 768 + obase + ch * 8) =
          *reinterpret_cast<const uint4*>(sC + row * 136 + ch * 8);
    }
  } else {
#pragma unroll
    for (int in = 0; in < 4; ++in) {
      int ol = wn + in * 16 + l16;
      float bv_ = bias[n0 + ol];
#pragma unroll
      for (int im = 0; im < 4; ++im)
#pragma unroll
        for (int r = 0; r < 4; ++r) {
          int mr = wm + im * 16 + quad * 4 + r;
          sC[ol * 136 + mr] = f2b(acc[im][in][r] + bv_);
        }
    }
    __syncthreads();
#pragma unroll
    for (int i = 0; i < 8; ++i) {
      int cid = i * 256 + tid;
      int o = cid >> 4, ch = cid & 15;
      *reinterpret_cast<uint4*>(pV + (size_t)(obase + o) * M + m0 + ch * 8) =
          *reinterpret_cast<const uint4*>(sC + o * 136 + ch * 8);
    }
  }
}

// ---------------------------------------------------------------------------
// Fused proj GEMM + residual (video blocks 0..767, audio 768..959)
// ---------------------------------------------------------------------------
__global__ __launch_bounds__(256) void proj_fused_kernel(
    const ushort_t* __restrict__ Ov, const ushort_t* __restrict__ Oa,
    const ushort_t* __restrict__ Wpv, const ushort_t* __restrict__ Wpa,
    const float* __restrict__ vproj_b, const float* __restrict__ aproj_b,
    float* __restrict__ out_v, const float* __restrict__ video,
    float* __restrict__ out_a, const float* __restrict__ audio) {
  __shared__ ushort_t sm[32768];
  const int bid = blockIdx.x;
  const int tid = threadIdx.x;
  const int lane = tid & 63, wave = tid >> 6;
  const int quad = lane >> 4, l16 = lane & 15;

  const bool isv = bid < 768;
  const int lb = isv ? bid : bid - 768;
  const int nwg = isv ? 768 : 192;
  const ushort_t* A = isv ? Ov : Oa;
  const ushort_t* W = isv ? Wpv : Wpa;
  const float* bias = isv ? vproj_b : aproj_b;
  float* outp = isv ? out_v : out_a;
  const float* resp = isv ? video : audio;

  const int lid = (lb & 7) * (nwg >> 3) + (lb >> 3);
  const int n0 = (lid % 6) * 128, m0 = (lid / 6) * 128;
  const int wm = (wave & 1) * 64, wn = (wave >> 1) * 64;

  const int srow = wave * 32 + (lane >> 3);
  const int sq = ((lane & 7) ^ (lane >> 3)) * 8;
  const ushort_t* gA = A + (size_t)(m0 + srow) * 768 + sq;
  const ushort_t* gB = W + (size_t)(n0 + srow) * 768 + sq;

  f32x4 acc[4][4];
#pragma unroll
  for (int i = 0; i < 4; ++i)
#pragma unroll
    for (int j = 0; j < 4; ++j) acc[i][j] = (f32x4){0.f, 0.f, 0.f, 0.f};

  auto stage = [&](int kc, int cur) {
    ushort_t* lA = sm + cur * 8192 + wave * 2048;
    ushort_t* lB = sm + 16384 + cur * 8192 + wave * 2048;
#pragma unroll
    for (int i = 0; i < 4; ++i) {
      gl_lds16(gA + (size_t)i * 8 * 768 + kc, lA + i * 512);
      gl_lds16(gB + (size_t)i * 8 * 768 + kc, lB + i * 512);
    }
  };

  stage(0, 0);
  __syncthreads();
  int cur = 0;
  for (int t = 0; t < 12; ++t) {
    if (t < 11) stage((t + 1) * 64, cur ^ 1);
    const ushort_t* cA = sm + cur * 8192;
    const ushort_t* cB = sm + 16384 + cur * 8192;
#pragma unroll
    for (int ks = 0; ks < 2; ++ks) {
      short8 av[4], bv[4];
#pragma unroll
      for (int im = 0; im < 4; ++im) {
        int rr = wm + im * 16 + l16;
        av[im] = *reinterpret_cast<const short8*>(
            cA + rr * 64 + (((ks * 4 + quad) ^ (rr & 7)) * 8));
      }
#pragma unroll
      for (int in = 0; in < 4; ++in) {
        int rr = wn + in * 16 + l16;
        bv[in] = *reinterpret_cast<const short8*>(
            cB + rr * 64 + (((ks * 4 + quad) ^ (rr & 7)) * 8));
      }
#pragma unroll
      for (int im = 0; im < 4; ++im)
#pragma unroll
        for (int in = 0; in < 4; ++in)
          acc[im][in] = __builtin_amdgcn_mfma_f32_16x16x32_bf16(av[im], bv[in], acc[im][in], 0, 0, 0);
    }
    __syncthreads();
    cur ^= 1;
  }

  ushort_t* sC = sm;  // [128 o][136] bf16, transposed store
#pragma unroll
  for (int in = 0; in < 4; ++in) {
    int ol = wn + in * 16 + l16;
    float bv_ = bias[n0 + ol];
#pragma unroll
    for (int im = 0; im < 4; ++im)
#pragma unroll
      for (int r = 0; r < 4; ++r) {
        int mr = wm + im * 16 + quad * 4 + r;
        sC[ol * 136 + mr] = f2b(acc[im][in][r] + bv_);
      }
  }
  __syncthreads();
#pragma unroll
  for (int i = 0; i < 16; ++i) {
    int cid = i * 256 + tid;
    int o = cid >> 5, ch = cid & 31;
    uint2 pk = *reinterpret_cast<const uint2*>(sC + o * 136 + ch * 4);
    size_t gidx;
    if (isv) {
      int b = m0 >> 12, f = (m0 >> 8) & 15, hw0 = m0 & 255;
      gidx = ((size_t)((b * 16 + f) * 768 + n0 + o)) * 256 + hw0 + ch * 4;
    } else {
      int b = m0 >> 10, t0 = m0 & 1023;
      gidx = ((size_t)(b * 768 + n0 + o)) * 1024 + t0 + ch * 4;
    }
    float4 rv = *reinterpret_cast<const float4*>(resp + gidx);
    float4 ov;
    ov.x = rv.x + b2f(pk.x & 0xffff);
    ov.y = rv.y + b2f(pk.x >> 16);
    ov.z = rv.z + b2f(pk.y & 0xffff);
    ov.w = rv.w + b2f(pk.y >> 16);
    *reinterpret_cast<float4*>(outp + gidx) = ov;
  }
}

// ---------------------------------------------------------------------------
// Fused MFMA flash attention, NO K/V LDS staging (windows are L2-resident and
// shared by 4-16 blocks; Common-mistake #7). Q/K/V fragments read directly
// from global; only LDS use is the wave-private P buffer -> ZERO barriers in
// the main loop. XCD-chunked block swizzle keeps window-sharing blocks on one
// XCD's L2. Math is bit-identical to the staged version.
// Blocks (decoded) 0..3071: video-q/audio-kv (QW=1024,SW=256);
// 3072..3839: audio-q/video-kv (QW=256,SW=1024).
// ---------------------------------------------------------------------------
__global__ __launch_bounds__(256) void attn_fused_kernel(
    const ushort_t* __restrict__ Qv, const ushort_t* __restrict__ Ka,
    const ushort_t* __restrict__ Va, ushort_t* __restrict__ Ov,
    const ushort_t* __restrict__ Qa, const ushort_t* __restrict__ Kv,
    const ushort_t* __restrict__ Vv, ushort_t* __restrict__ Oa) {
  __shared__ ushort_t sP[64 * 136];    // 17408 B: P bf16 / O bounce (wave-private rows)
  const int tid = threadIdx.x;
  const int lane = tid & 63, wave = tid >> 6;
  const int quad = lane >> 4, l16 = lane & 15;

  // XCD swizzle: 3840 = 8 * 480; window-sharing (consecutive) ids stay on one XCD
  const int bx0 = blockIdx.x;
  const int bx = (bx0 & 7) * 480 + (bx0 >> 3);

  const bool isv = bx < 3072;
  const ushort_t* Qt = isv ? Qv : Qa;
  const ushort_t* Kt = isv ? Ka : Kv;
  const ushort_t* Vc = isv ? Va : Vv;
  ushort_t* Ot = isv ? Ov : Oa;
  const int lb = isv ? bx : bx - 3072;
  const int qlog = isv ? 4 : 2;        // NQT = 16 / 4
  const int NT = isv ? 2 : 8;          // SW/128
  const int QW = isv ? 1024 : 256;
  const int SW = isv ? 256 : 1024;
  const int TQb = isv ? 4096 : 1024;
  const int TSb = isv ? 1024 : 4096;
  const int Ms = isv ? 4096 : 16384;

  const int qt = lb & ((1 << qlog) - 1);
  const int win = (lb >> qlog) & 3;
  const int whb = lb >> (qlog + 2);
  const int h = whb % 12;
  const int batch = whb / 12;
  const int hc = h * 64;
  const int nq0 = batch * TQb + win * QW + qt * 64;
  const int ns_base = batch * TSb + win * SW;

  // Q fragments: direct global read (row = nq0 + wave*16 + l16)
  const ushort_t* qp = Qt + (size_t)(nq0 + wave * 16 + l16) * 768 + hc;
  short8 qf[2];
#pragma unroll
  for (int ks = 0; ks < 2; ++ks)
    qf[ks] = *reinterpret_cast<const short8*>(qp + ks * 32 + quad * 8);

  float mr[4], lr[4];
  f32x4 on[4];
#pragma unroll
  for (int r = 0; r < 4; ++r) { mr[r] = -1e30f; lr[r] = 0.f; }
#pragma unroll
  for (int nc = 0; nc < 4; ++nc) on[nc] = (f32x4){0.f, 0.f, 0.f, 0.f};

  const ushort_t* kbase = Kt + (size_t)(ns_base + l16) * 768 + hc + quad * 8;
  const ushort_t* vbase = Vc + (size_t)(hc + l16) * Ms + ns_base + quad * 8;
  const int prow0 = (wave * 16 + quad * 4) * 136;

  for (int t = 0; t < NT; ++t) {
    const int toff = t * 128;
    // ---- S = Q K^T : K fragments direct from global (L1/L2-served)
    f32x4 sf[8];
#pragma unroll
    for (int nt = 0; nt < 8; ++nt) sf[nt] = (f32x4){0.f, 0.f, 0.f, 0.f};
#pragma unroll
    for (int ks = 0; ks < 2; ++ks) {
#pragma unroll
      for (int nt = 0; nt < 8; ++nt) {
        short8 kf = *reinterpret_cast<const short8*>(
            kbase + (size_t)(toff + nt * 16) * 768 + ks * 32);
        sf[nt] = __builtin_amdgcn_mfma_f32_16x16x32_bf16(qf[ks], kf, sf[nt], 0, 0, 0);
      }
    }
    // ---- online softmax (rows wave*16+quad*4+r are wave-private in sP)
#pragma unroll
    for (int r = 0; r < 4; ++r) {
      float m_ = sf[0][r];
#pragma unroll
      for (int nt = 1; nt < 8; ++nt) m_ = fmaxf(m_, sf[nt][r]);
#pragma unroll
      for (int off = 1; off < 16; off <<= 1) m_ = fmaxf(m_, __shfl_xor(m_, off));
      float mnew = fmaxf(mr[r], m_);
      float al = __expf(mr[r] - mnew);
      float ls = 0.f;
      int prow = prow0 + r * 136;
#pragma unroll
      for (int nt = 0; nt < 8; ++nt) {
        float p = __expf(sf[nt][r] - mnew);
        ls += p;
        sP[prow + nt * 16 + l16] = f2b(p);
      }
#pragma unroll
      for (int off = 1; off < 16; off <<= 1) ls += __shfl_xor(ls, off);
      lr[r] = lr[r] * al + ls;
      mr[r] = mnew;
#pragma unroll
      for (int nc = 0; nc < 4; ++nc) on[nc][r] *= al;
    }
    // ---- O += P V : V fragments direct from global (channel-major)
#pragma unroll
    for (int ks = 0; ks < 4; ++ks) {
      short8 pf = *reinterpret_cast<const short8*>(sP + (wave * 16 + l16) * 136 + ks * 32 + quad * 8);
#pragma unroll
      for (int nc = 0; nc < 4; ++nc) {
        short8 vf = *reinterpret_cast<const short8*>(
            vbase + (size_t)(nc * 16) * Ms + toff + ks * 32);
        on[nc] = __builtin_amdgcn_mfma_f32_16x16x32_bf16(pf, vf, on[nc], 0, 0, 0);
      }
    }
  }
  // ---- finalize: O /= l, bounce through sP for coalesced writes
#pragma unroll
  for (int r = 0; r < 4; ++r) {
    float inv = 1.f / lr[r];
    int prow = prow0 + r * 136;
#pragma unroll
    for (int nc = 0; nc < 4; ++nc)
      sP[prow + nc * 16 + l16] = f2b(on[nc][r] * inv);
  }
  __syncthreads();
#pragma unroll
  for (int i = 0; i < 2; ++i) {
    int c = i * 256 + tid;
    int row = c >> 3, cc = c & 7;
    *reinterpret_cast<uint4*>(Ot + (size_t)(nq0 + row) * 768 + hc + cc * 8) =
        *reinterpret_cast<const uint4*>(sP + row * 136 + cc * 8);
  }
}

// ---------------------------------------------------------------------------
extern "C" void kernel_launch(void* const* d_in, const int* in_sizes, int n_in,
                              void* d_out, int out_size, void* d_ws, size_t ws_size,
                              hipStream_t stream) {
  (void)in_sizes; (void)n_in; (void)out_size; (void)ws_size;
  const float* video = (const float*)d_in[0];
  const float* audio = (const float*)d_in[1];
  const float* vn_s = (const float*)d_in[2];
  const float* vn_b = (const float*)d_in[3];
  const float* an_s = (const float*)d_in[4];
  const float* an_b = (const float*)d_in[5];
  const float* vqkv_w = (const float*)d_in[6];
  const float* vqkv_b = (const float*)d_in[7];
  const float* aqkv_w = (const float*)d_in[8];
  const float* aqkv_b = (const float*)d_in[9];
  const float* vproj_w = (const float*)d_in[10];
  const float* vproj_b = (const float*)d_in[11];
  const float* aproj_w = (const float*)d_in[12];
  const float* aproj_b = (const float*)d_in[13];

  float* out_v = (float*)d_out;
  float* out_a = out_v + (size_t)4 * 16 * 768 * 16 * 16;

  char* ws = (char*)d_ws;
  size_t off = 0;
  auto carve = [&](size_t bytes) {
    char* p = ws + off;
    off += (bytes + 255) & ~(size_t)255;
    return p;
  };
  float* part = (float*)carve(2560 * 2 * 4);
  ushort_t* Xv = (ushort_t*)carve((size_t)16384 * 768 * 2);
  ushort_t* Xa = (ushort_t*)carve((size_t)4096 * 768 * 2);
  ushort_t* Wqv = (ushort_t*)carve((size_t)2304 * 768 * 2);
  ushort_t* Wqa = (ushort_t*)carve((size_t)2304 * 768 * 2);
  ushort_t* Wpv = (ushort_t*)carve((size_t)768 * 768 * 2);
  ushort_t* Wpa = (ushort_t*)carve((size_t)768 * 768 * 2);
  ushort_t* Qv = (ushort_t*)carve((size_t)16384 * 768 * 2);
  ushort_t* Kv = (ushort_t*)carve((size_t)16384 * 768 * 2);
  ushort_t* Vv = (ushort_t*)carve((size_t)16384 * 768 * 2);
  ushort_t* Qa = (ushort_t*)carve((size_t)4096 * 768 * 2);
  ushort_t* Ka = (ushort_t*)carve((size_t)4096 * 768 * 2);
  ushort_t* Va = (ushort_t*)carve((size_t)4096 * 768 * 2);
  ushort_t* Ov = Xv;  // alias: X no longer needed after QKV GEMM
  ushort_t* Oa = Xa;

  fused_pre_kernel<<<3584, 256, 0, stream>>>(video, audio, part,
                                             vqkv_w, aqkv_w, vproj_w, aproj_w,
                                             Wqv, Wqa, Wpv, Wpa);
  norm_fused_kernel<<<1920, 256, 0, stream>>>(video, audio, part,
                                              vn_s, vn_b, an_s, an_b, Xv, Xa);
  qkv_fused_kernel<<<2880, 256, 0, stream>>>(Xv, Xa, Wqv, Wqa, vqkv_b, aqkv_b,
                                             Qv, Kv, Vv, Qa, Ka, Va);
  attn_fused_kernel<<<3840, 256, 0, stream>>>(Qv, Ka, Va, Ov, Qa, Kv, Vv, Oa);
  proj_fused_kernel<<<960, 256, 0, stream>>>(Ov, Oa, Wpv, Wpa, vproj_b, aproj_b,
                                             out_v, video, out_a, audio);
}

// Round 7
// 459.224 us; speedup vs baseline: 1.5358x; 1.5358x over previous
//
#include <hip/hip_runtime.h>
#include <hip/hip_bf16.h>

typedef unsigned short ushort_t;
typedef __attribute__((ext_vector_type(8))) short short8;
typedef __attribute__((ext_vector_type(4))) float f32x4;

#define DI __device__ __forceinline__

DI float b2f(unsigned int u16) {
  union { unsigned int i; float f; } v;
  v.i = u16 << 16;
  return v.f;
}
DI ushort_t f2b(float f) {
  union { float f; unsigned int u; } v; v.f = f;
  unsigned int r = v.u + 0x7FFFu + ((v.u >> 16) & 1u);
  return (ushort_t)(r >> 16);
}

// async global->LDS 16B copy: LDS dest is wave-uniform base + lane*16
DI void gl_lds16(const ushort_t* g, ushort_t* l) {
  __builtin_amdgcn_global_load_lds(
      (const __attribute__((address_space(1))) unsigned int*)g,
      (__attribute__((address_space(3))) unsigned int*)l, 16, 0, 0);
}

// ---------------------------------------------------------------------------
// Fused: GroupNorm partial stats (blocks 0..2559) + weight bf16 cvt (2560..3583)
// ---------------------------------------------------------------------------
__global__ __launch_bounds__(256) void fused_pre_kernel(
    const float* __restrict__ video, const float* __restrict__ audio,
    float* __restrict__ part,
    const float* __restrict__ w0, const float* __restrict__ w1,
    const float* __restrict__ w2, const float* __restrict__ w3,
    ushort_t* __restrict__ o0, ushort_t* __restrict__ o1,
    ushort_t* __restrict__ o2, ushort_t* __restrict__ o3) {
  const int bid = blockIdx.x;
  const int tid = threadIdx.x;
  __shared__ float red[8];
  if (bid < 2560) {
    float s = 0.f, ss = 0.f;
    if (bid < 2048) {
      int bg = bid >> 4, f = bid & 15;
      int b = bg >> 5, g = bg & 31;
      const float* base = video + ((size_t)((b * 16 + f) * 768 + g * 24)) * 256 + tid;
#pragma unroll
      for (int cl = 0; cl < 24; ++cl) {
        float v = base[cl * 256];
        s += v; ss += v * v;
      }
    } else {
      int a = bid - 2048;
      int bg = a >> 2, p = a & 3;
      int b = bg >> 5, g = bg & 31;
      const float* base = audio + ((size_t)(b * 768 + g * 24)) * 1024 + p * 256 + tid;
#pragma unroll
      for (int cl = 0; cl < 24; ++cl) {
        float v = base[cl * 1024];
        s += v; ss += v * v;
      }
    }
    for (int off = 32; off > 0; off >>= 1) { s += __shfl_down(s, off, 64); ss += __shfl_down(ss, off, 64); }
    int wv = tid >> 6, ln = tid & 63;
    if (ln == 0) { red[wv * 2] = s; red[wv * 2 + 1] = ss; }
    __syncthreads();
    if (tid == 0) {
      part[bid * 2] = red[0] + red[2] + red[4] + red[6];
      part[bid * 2 + 1] = red[1] + red[3] + red[5] + red[7];
    }
  } else {
    const int n1 = 2304 * 768, n3 = 768 * 768;
    const int total = 2 * n1 + 2 * n3;
    int wb = bid - 2560;
    for (int i = wb * 256 + tid; i < total; i += 1024 * 256) {
      if (i < n1) o0[i] = f2b(w0[i]);
      else if (i < 2 * n1) o1[i - n1] = f2b(w1[i - n1]);
      else if (i < 2 * n1 + n3) o2[i - 2 * n1] = f2b(w2[i - 2 * n1]);
      else o3[i - 2 * n1 - n3] = f2b(w3[i - 2 * n1 - n3]);
    }
  }
}

// ---------------------------------------------------------------------------
// Fused normalize (gn_final folded in: per-block channel stats from `part`).
// Blocks 0..1535: video -> Xv[n][c]; 1536..1919: audio -> Xa[n][c].
// ---------------------------------------------------------------------------
__global__ __launch_bounds__(256) void norm_fused_kernel(
    const float* __restrict__ video, const float* __restrict__ audio,
    const float* __restrict__ part,
    const float* __restrict__ vsc, const float* __restrict__ vbi,
    const float* __restrict__ asc, const float* __restrict__ abi,
    ushort_t* __restrict__ Xv, ushort_t* __restrict__ Xa) {
  __shared__ float T[32][257];
  __shared__ float shm[32], shr[32];
  const int bx = blockIdx.x;
  const int tid = threadIdx.x;
  if (bx < 1536) {
    const int bf = bx / 24, ct = bx % 24;
    const int b = bf >> 4, f = bf & 15;
    const int c0 = ct * 32;
    if (tid < 32) {
      int c = c0 + tid, g = c / 24;
      float s = 0.f, ss = 0.f;
#pragma unroll
      for (int i = 0; i < 16; ++i) {
        s += part[((b * 32 + g) * 16 + i) * 2];
        ss += part[((b * 32 + g) * 16 + i) * 2 + 1];
      }
      const float N = 24.f * 4096.f;
      float m = s / N;
      shm[tid] = m;
      shr[tid] = rsqrtf(ss / N - m * m + 1e-5f);
    }
    __syncthreads();
    for (int i = 0; i < 32; ++i) {
      int c = c0 + i;
      float v = video[((size_t)((b * 16 + f) * 768 + c)) * 256 + tid];
      T[i][tid] = (v - shm[i]) * shr[i] * vsc[c] + vbi[c];
    }
    __syncthreads();
    for (int i = 0; i < 32; ++i) {
      int id = i * 256 + tid;
      int c = id & 31, hw = id >> 5;
      Xv[((size_t)(b * 4096 + f * 256 + hw)) * 768 + c0 + c] = f2b(T[c][hw]);
    }
  } else {
    const int ax = bx - 1536;
    const int bt = ax / 24, ct = ax % 24;
    const int b = bt >> 2, t0 = (bt & 3) * 256;
    const int c0 = ct * 32;
    if (tid < 32) {
      int c = c0 + tid, g = c / 24;
      float s = 0.f, ss = 0.f;
#pragma unroll
      for (int i = 0; i < 4; ++i) {
        s += part[(2048 + (b * 32 + g) * 4 + i) * 2];
        ss += part[(2048 + (b * 32 + g) * 4 + i) * 2 + 1];
      }
      const float N = 24.f * 1024.f;
      float m = s / N;
      shm[tid] = m;
      shr[tid] = rsqrtf(ss / N - m * m + 1e-5f);
    }
    __syncthreads();
    for (int i = 0; i < 32; ++i) {
      int c = c0 + i;
      float v = audio[((size_t)(b * 768 + c)) * 1024 + t0 + tid];
      T[i][tid] = (v - shm[i]) * shr[i] * asc[c] + abi[c];
    }
    __syncthreads();
    for (int i = 0; i < 32; ++i) {
      int id = i * 256 + tid;
      int c = id & 31, tt = id >> 5;
      Xa[((size_t)(b * 1024 + t0 + tt)) * 768 + c0 + c] = f2b(T[c][tt]);
    }
  }
}

// ---------------------------------------------------------------------------
// Fused QKV GEMM (video blocks 0..2303, audio 2304..2879).
// 128x128 tile, 2-phase dbuf gl_lds16 staging, XOR chunk swizzle both sides,
// segment-local XCD bijective block swizzle.
// Q section pre-scaled by 0.125*log2(e): attention softmax runs in exp2 domain.
// ---------------------------------------------------------------------------
__global__ __launch_bounds__(256) void qkv_fused_kernel(
    const ushort_t* __restrict__ Xv, const ushort_t* __restrict__ Xa,
    const ushort_t* __restrict__ Wqv, const ushort_t* __restrict__ Wqa,
    const float* __restrict__ vqkv_b, const float* __restrict__ aqkv_b,
    ushort_t* __restrict__ Qv, ushort_t* __restrict__ Kv, ushort_t* __restrict__ Vv,
    ushort_t* __restrict__ Qa, ushort_t* __restrict__ Ka, ushort_t* __restrict__ Va) {
  __shared__ ushort_t sm[32768];  // 64 KiB dbuf
  const int bid = blockIdx.x;
  const int tid = threadIdx.x;
  const int lane = tid & 63, wave = tid >> 6;
  const int quad = lane >> 4, l16 = lane & 15;

  const bool isv = bid < 2304;
  const int lb = isv ? bid : bid - 2304;
  const int nwg = isv ? 2304 : 576;
  const ushort_t* A = isv ? Xv : Xa;
  const ushort_t* W = isv ? Wqv : Wqa;
  const float* bias = isv ? vqkv_b : aqkv_b;
  ushort_t* pQ = isv ? Qv : Qa;
  ushort_t* pK = isv ? Kv : Ka;
  ushort_t* pV = isv ? Vv : Va;
  const int M = isv ? 16384 : 4096;

  const int lid = (lb & 7) * (nwg >> 3) + (lb >> 3);
  const int n0 = (lid % 18) * 128, m0 = (lid / 18) * 128;
  const int wm = (wave & 1) * 64, wn = (wave >> 1) * 64;

  const int srow = wave * 32 + (lane >> 3);
  const int sq = ((lane & 7) ^ (lane >> 3)) * 8;
  const ushort_t* gA = A + (size_t)(m0 + srow) * 768 + sq;
  const ushort_t* gB = W + (size_t)(n0 + srow) * 768 + sq;

  f32x4 acc[4][4];
#pragma unroll
  for (int i = 0; i < 4; ++i)
#pragma unroll
    for (int j = 0; j < 4; ++j) acc[i][j] = (f32x4){0.f, 0.f, 0.f, 0.f};

  auto stage = [&](int kc, int cur) {
    ushort_t* lA = sm + cur * 8192 + wave * 2048;
    ushort_t* lB = sm + 16384 + cur * 8192 + wave * 2048;
#pragma unroll
    for (int i = 0; i < 4; ++i) {
      gl_lds16(gA + (size_t)i * 8 * 768 + kc, lA + i * 512);
      gl_lds16(gB + (size_t)i * 8 * 768 + kc, lB + i * 512);
    }
  };

  stage(0, 0);
  __syncthreads();
  int cur = 0;
  for (int t = 0; t < 12; ++t) {
    if (t < 11) stage((t + 1) * 64, cur ^ 1);
    const ushort_t* cA = sm + cur * 8192;
    const ushort_t* cB = sm + 16384 + cur * 8192;
#pragma unroll
    for (int ks = 0; ks < 2; ++ks) {
      short8 av[4], bv[4];
#pragma unroll
      for (int im = 0; im < 4; ++im) {
        int rr = wm + im * 16 + l16;
        av[im] = *reinterpret_cast<const short8*>(
            cA + rr * 64 + (((ks * 4 + quad) ^ (rr & 7)) * 8));
      }
#pragma unroll
      for (int in = 0; in < 4; ++in) {
        int rr = wn + in * 16 + l16;
        bv[in] = *reinterpret_cast<const short8*>(
            cB + rr * 64 + (((ks * 4 + quad) ^ (rr & 7)) * 8));
      }
#pragma unroll
      for (int im = 0; im < 4; ++im)
#pragma unroll
        for (int in = 0; in < 4; ++in)
          acc[im][in] = __builtin_amdgcn_mfma_f32_16x16x32_bf16(av[im], bv[in], acc[im][in], 0, 0, 0);
    }
    __syncthreads();
    cur ^= 1;
  }

  ushort_t* sC = sm;  // epilogue scratch [128][136] bf16
  const int section = n0 / 768;  // 0=Q 1=K 2=V
  const int obase = n0 - section * 768;
  if (section < 2) {
    // fold qk scale AND log2(e) into Q: softmax uses native exp2
    const float qs = (section == 0) ? 0.125f * 1.44269504088896340736f : 1.0f;
#pragma unroll
    for (int in = 0; in < 4; ++in) {
      int ol = wn + in * 16 + l16;
      float bv_ = bias[n0 + ol];
#pragma unroll
      for (int im = 0; im < 4; ++im)
#pragma unroll
        for (int r = 0; r < 4; ++r) {
          int row = wm + im * 16 + quad * 4 + r;
          sC[row * 136 + ol] = f2b((acc[im][in][r] + bv_) * qs);
        }
    }
    __syncthreads();
    ushort_t* dst = (section == 0) ? pQ : pK;
#pragma unroll
    for (int i = 0; i < 8; ++i) {
      int cid = i * 256 + tid;
      int row = cid >> 4, ch = cid & 15;
      *reinterpret_cast<uint4*>(dst + (size_t)(m0 + row) * 768 + obase + ch * 8) =
          *reinterpret_cast<const uint4*>(sC + row * 136 + ch * 8);
    }
  } else {
#pragma unroll
    for (int in = 0; in < 4; ++in) {
      int ol = wn + in * 16 + l16;
      float bv_ = bias[n0 + ol];
#pragma unroll
      for (int im = 0; im < 4; ++im)
#pragma unroll
        for (int r = 0; r < 4; ++r) {
          int mr = wm + im * 16 + quad * 4 + r;
          sC[ol * 136 + mr] = f2b(acc[im][in][r] + bv_);
        }
    }
    __syncthreads();
#pragma unroll
    for (int i = 0; i < 8; ++i) {
      int cid = i * 256 + tid;
      int o = cid >> 4, ch = cid & 15;
      *reinterpret_cast<uint4*>(pV + (size_t)(obase + o) * M + m0 + ch * 8) =
          *reinterpret_cast<const uint4*>(sC + o * 136 + ch * 8);
    }
  }
}

// ---------------------------------------------------------------------------
// Fused proj GEMM + residual (video blocks 0..767, audio 768..959)
// ---------------------------------------------------------------------------
__global__ __launch_bounds__(256) void proj_fused_kernel(
    const ushort_t* __restrict__ Ov, const ushort_t* __restrict__ Oa,
    const ushort_t* __restrict__ Wpv, const ushort_t* __restrict__ Wpa,
    const float* __restrict__ vproj_b, const float* __restrict__ aproj_b,
    float* __restrict__ out_v, const float* __restrict__ video,
    float* __restrict__ out_a, const float* __restrict__ audio) {
  __shared__ ushort_t sm[32768];
  const int bid = blockIdx.x;
  const int tid = threadIdx.x;
  const int lane = tid & 63, wave = tid >> 6;
  const int quad = lane >> 4, l16 = lane & 15;

  const bool isv = bid < 768;
  const int lb = isv ? bid : bid - 768;
  const int nwg = isv ? 768 : 192;
  const ushort_t* A = isv ? Ov : Oa;
  const ushort_t* W = isv ? Wpv : Wpa;
  const float* bias = isv ? vproj_b : aproj_b;
  float* outp = isv ? out_v : out_a;
  const float* resp = isv ? video : audio;

  const int lid = (lb & 7) * (nwg >> 3) + (lb >> 3);
  const int n0 = (lid % 6) * 128, m0 = (lid / 6) * 128;
  const int wm = (wave & 1) * 64, wn = (wave >> 1) * 64;

  const int srow = wave * 32 + (lane >> 3);
  const int sq = ((lane & 7) ^ (lane >> 3)) * 8;
  const ushort_t* gA = A + (size_t)(m0 + srow) * 768 + sq;
  const ushort_t* gB = W + (size_t)(n0 + srow) * 768 + sq;

  f32x4 acc[4][4];
#pragma unroll
  for (int i = 0; i < 4; ++i)
#pragma unroll
    for (int j = 0; j < 4; ++j) acc[i][j] = (f32x4){0.f, 0.f, 0.f, 0.f};

  auto stage = [&](int kc, int cur) {
    ushort_t* lA = sm + cur * 8192 + wave * 2048;
    ushort_t* lB = sm + 16384 + cur * 8192 + wave * 2048;
#pragma unroll
    for (int i = 0; i < 4; ++i) {
      gl_lds16(gA + (size_t)i * 8 * 768 + kc, lA + i * 512);
      gl_lds16(gB + (size_t)i * 8 * 768 + kc, lB + i * 512);
    }
  };

  stage(0, 0);
  __syncthreads();
  int cur = 0;
  for (int t = 0; t < 12; ++t) {
    if (t < 11) stage((t + 1) * 64, cur ^ 1);
    const ushort_t* cA = sm + cur * 8192;
    const ushort_t* cB = sm + 16384 + cur * 8192;
#pragma unroll
    for (int ks = 0; ks < 2; ++ks) {
      short8 av[4], bv[4];
#pragma unroll
      for (int im = 0; im < 4; ++im) {
        int rr = wm + im * 16 + l16;
        av[im] = *reinterpret_cast<const short8*>(
            cA + rr * 64 + (((ks * 4 + quad) ^ (rr & 7)) * 8));
      }
#pragma unroll
      for (int in = 0; in < 4; ++in) {
        int rr = wn + in * 16 + l16;
        bv[in] = *reinterpret_cast<const short8*>(
            cB + rr * 64 + (((ks * 4 + quad) ^ (rr & 7)) * 8));
      }
#pragma unroll
      for (int im = 0; im < 4; ++im)
#pragma unroll
        for (int in = 0; in < 4; ++in)
          acc[im][in] = __builtin_amdgcn_mfma_f32_16x16x32_bf16(av[im], bv[in], acc[im][in], 0, 0, 0);
    }
    __syncthreads();
    cur ^= 1;
  }

  ushort_t* sC = sm;  // [128 o][136] bf16, transposed store
#pragma unroll
  for (int in = 0; in < 4; ++in) {
    int ol = wn + in * 16 + l16;
    float bv_ = bias[n0 + ol];
#pragma unroll
    for (int im = 0; im < 4; ++im)
#pragma unroll
      for (int r = 0; r < 4; ++r) {
        int mr = wm + im * 16 + quad * 4 + r;
        sC[ol * 136 + mr] = f2b(acc[im][in][r] + bv_);
      }
  }
  __syncthreads();
#pragma unroll
  for (int i = 0; i < 16; ++i) {
    int cid = i * 256 + tid;
    int o = cid >> 5, ch = cid & 31;
    uint2 pk = *reinterpret_cast<const uint2*>(sC + o * 136 + ch * 4);
    size_t gidx;
    if (isv) {
      int b = m0 >> 12, f = (m0 >> 8) & 15, hw0 = m0 & 255;
      gidx = ((size_t)((b * 16 + f) * 768 + n0 + o)) * 256 + hw0 + ch * 4;
    } else {
      int b = m0 >> 10, t0 = m0 & 1023;
      gidx = ((size_t)(b * 768 + n0 + o)) * 1024 + t0 + ch * 4;
    }
    float4 rv = *reinterpret_cast<const float4*>(resp + gidx);
    float4 ov;
    ov.x = rv.x + b2f(pk.x & 0xffff);
    ov.y = rv.y + b2f(pk.x >> 16);
    ov.z = rv.z + b2f(pk.y & 0xffff);
    ov.w = rv.w + b2f(pk.y >> 16);
    *reinterpret_cast<float4*>(outp + gidx) = ov;
  }
}

// ---------------------------------------------------------------------------
// Fused MFMA flash attention (staged LDS path restored from round 5 -- the
// direct-global variant was latency-bound at 2% MFMA).
// New this round: XCD chunk swizzle (window-sharing blocks on one XCD's L2);
// softmax in exp2 domain (Q pre-scaled by log2 e in GEMM); row-sum via a
// 5th ones-MFMA in PV (replaces 4-stage shuffle-add reduce); round-half-up
// single-add P->bf16 conversion; max3 chains for in-thread max.
// Blocks (decoded) 0..3071: video-q/audio-kv (QW=1024,SW=256);
// 3072..3839: audio-q/video-kv (QW=256,SW=1024).
// ---------------------------------------------------------------------------
__global__ __launch_bounds__(256) void attn_fused_kernel(
    const ushort_t* __restrict__ Qv, const ushort_t* __restrict__ Ka,
    const ushort_t* __restrict__ Va, ushort_t* __restrict__ Ov,
    const ushort_t* __restrict__ Qa, const ushort_t* __restrict__ Kv,
    const ushort_t* __restrict__ Vv, ushort_t* __restrict__ Oa) {
  __shared__ ushort_t sm[37376];       // 74752 B
  ushort_t* sQ = sm;                   // [64][64]  xor8
  ushort_t* sK = sm + 4096;            // [128][64] xor8
  ushort_t* sV0 = sm + 12288;          // [64][128] xor16
  ushort_t* sV1 = sm + 20480;
  ushort_t* sP = sm + 28672;           // [64][136] P bf16 / O bounce
  const int tid = threadIdx.x;
  const int lane = tid & 63, wave = tid >> 6;
  const int quad = lane >> 4, l16 = lane & 15;

  // XCD swizzle: 3840 = 8 * 480; window-sharing (consecutive) ids on one XCD
  const int bx0 = blockIdx.x;
  const int bx = (bx0 & 7) * 480 + (bx0 >> 3);

  const bool isv = bx < 3072;
  const ushort_t* Qt = isv ? Qv : Qa;
  const ushort_t* Kt = isv ? Ka : Kv;
  const ushort_t* Vc = isv ? Va : Vv;
  ushort_t* Ot = isv ? Ov : Oa;
  const int lb = isv ? bx : bx - 3072;
  const int qlog = isv ? 4 : 2;        // NQT = 16 / 4
  const int NT = isv ? 2 : 8;          // SW/128
  const int QW = isv ? 1024 : 256;
  const int SW = isv ? 256 : 1024;
  const int TQb = isv ? 4096 : 1024;
  const int TSb = isv ? 1024 : 4096;
  const int Ms = isv ? 4096 : 16384;

  const int qt = lb & ((1 << qlog) - 1);
  const int win = (lb >> qlog) & 3;
  const int whb = lb >> (qlog + 2);
  const int h = whb % 12;
  const int batch = whb / 12;
  const int hc = h * 64;
  const int nq0 = batch * TQb + win * QW + qt * 64;
  const int ns_base = batch * TSb + win * SW;

  const int r8 = lane >> 3, c8 = lane & 7;
  const int s8 = (c8 ^ r8) * 8;
  const int r16 = lane >> 4, c16 = lane & 15;

  auto stage_k = [&](int ns0) {
#pragma unroll
    for (int i = 0; i < 4; ++i) {
      int row = wave * 32 + i * 8 + r8;
      gl_lds16(Kt + (size_t)(ns0 + row) * 768 + hc + s8, sK + (wave * 32 + i * 8) * 64);
    }
  };
  auto stage_v = [&](int ns0, ushort_t* sV) {
#pragma unroll
    for (int i = 0; i < 4; ++i) {
      int ch = wave * 16 + i * 4 + r16;
      int slot = c16 ^ (i * 4 + r16);
      gl_lds16(Vc + (size_t)(hc + ch) * Ms + ns0 + slot * 8, sV + (wave * 16 + i * 4) * 128);
    }
  };

#pragma unroll
  for (int i = 0; i < 2; ++i) {
    int row = wave * 16 + i * 8 + r8;
    gl_lds16(Qt + (size_t)(nq0 + row) * 768 + hc + s8, sQ + (wave * 16 + i * 8) * 64);
  }
  stage_k(ns_base);
  stage_v(ns_base, sV0);
  __syncthreads();

  short8 qf[2];
#pragma unroll
  for (int ks = 0; ks < 2; ++ks)
    qf[ks] = *reinterpret_cast<const short8*>(
        sQ + (wave * 16 + l16) * 64 + (((ks * 4 + quad) ^ (l16 & 7)) * 8));

  const short8 vones = {0x3F80, 0x3F80, 0x3F80, 0x3F80, 0x3F80, 0x3F80, 0x3F80, 0x3F80};

  float mr[4];
  f32x4 on[4], onl;
#pragma unroll
  for (int r = 0; r < 4; ++r) mr[r] = -1e30f;
#pragma unroll
  for (int nc = 0; nc < 4; ++nc) on[nc] = (f32x4){0.f, 0.f, 0.f, 0.f};
  onl = (f32x4){0.f, 0.f, 0.f, 0.f};
  const int prow0 = (wave * 16 + quad * 4) * 136;

  for (int t = 0; t < NT; ++t) {
    if (t + 1 < NT) stage_v(ns_base + (t + 1) * 128, (t & 1) ? sV0 : sV1);
    f32x4 sf[8];
#pragma unroll
    for (int nt = 0; nt < 8; ++nt) sf[nt] = (f32x4){0.f, 0.f, 0.f, 0.f};
#pragma unroll
    for (int ks = 0; ks < 2; ++ks) {
#pragma unroll
      for (int nt = 0; nt < 8; ++nt) {
        short8 kf = *reinterpret_cast<const short8*>(
            sK + (nt * 16 + l16) * 64 + (((ks * 4 + quad) ^ (l16 & 7)) * 8));
        sf[nt] = __builtin_amdgcn_mfma_f32_16x16x32_bf16(qf[ks], kf, sf[nt], 0, 0, 0);
      }
    }
    __syncthreads();
    if (t + 1 < NT) stage_k(ns_base + (t + 1) * 128);
    // ---- online softmax in exp2 domain; row-sum deferred to ones-MFMA
#pragma unroll
    for (int r = 0; r < 4; ++r) {
      float m_ = fmaxf(fmaxf(sf[0][r], sf[1][r]), sf[2][r]);
      m_ = fmaxf(fmaxf(m_, sf[3][r]), sf[4][r]);
      m_ = fmaxf(fmaxf(m_, sf[5][r]), sf[6][r]);
      m_ = fmaxf(m_, sf[7][r]);
#pragma unroll
      for (int off = 1; off < 16; off <<= 1) m_ = fmaxf(m_, __shfl_xor(m_, off));
      float mnew = fmaxf(mr[r], m_);
      float al = __builtin_amdgcn_exp2f(mr[r] - mnew);
      mr[r] = mnew;
      int prow = prow0 + r * 136;
#pragma unroll
      for (int nt = 0; nt < 8; ++nt) {
        float p = __builtin_amdgcn_exp2f(sf[nt][r] - mnew);
        sP[prow + nt * 16 + l16] = (ushort_t)((__float_as_uint(p) + 0x8000u) >> 16);
      }
#pragma unroll
      for (int nc = 0; nc < 4; ++nc) on[nc][r] *= al;
      onl[r] *= al;
    }
    // ---- O += P V ; l += P 1 (5th ones-MFMA replaces shuffle-add row-sum)
    const ushort_t* sV = (t & 1) ? sV1 : sV0;
#pragma unroll
    for (int ks = 0; ks < 4; ++ks) {
      short8 pf = *reinterpret_cast<const short8*>(sP + (wave * 16 + l16) * 136 + ks * 32 + quad * 8);
#pragma unroll
      for (int nc = 0; nc < 4; ++nc) {
        short8 vf = *reinterpret_cast<const short8*>(
            sV + (nc * 16 + l16) * 128 + (((ks * 4 + quad) ^ l16) * 8));
        on[nc] = __builtin_amdgcn_mfma_f32_16x16x32_bf16(pf, vf, on[nc], 0, 0, 0);
      }
      onl = __builtin_amdgcn_mfma_f32_16x16x32_bf16(pf, vones, onl, 0, 0, 0);
    }
    if (t + 1 < NT) __syncthreads();
  }
#pragma unroll
  for (int r = 0; r < 4; ++r) {
    float inv = 1.f / onl[r];
    int prow = prow0 + r * 136;
#pragma unroll
    for (int nc = 0; nc < 4; ++nc)
      sP[prow + nc * 16 + l16] = f2b(on[nc][r] * inv);
  }
  __syncthreads();
#pragma unroll
  for (int i = 0; i < 2; ++i) {
    int c = i * 256 + tid;
    int row = c >> 3, cc = c & 7;
    *reinterpret_cast<uint4*>(Ot + (size_t)(nq0 + row) * 768 + hc + cc * 8) =
        *reinterpret_cast<const uint4*>(sP + row * 136 + cc * 8);
  }
}

// ---------------------------------------------------------------------------
extern "C" void kernel_launch(void* const* d_in, const int* in_sizes, int n_in,
                              void* d_out, int out_size, void* d_ws, size_t ws_size,
                              hipStream_t stream) {
  (void)in_sizes; (void)n_in; (void)out_size; (void)ws_size;
  const float* video = (const float*)d_in[0];
  const float* audio = (const float*)d_in[1];
  const float* vn_s = (const float*)d_in[2];
  const float* vn_b = (const float*)d_in[3];
  const float* an_s = (const float*)d_in[4];
  const float* an_b = (const float*)d_in[5];
  const float* vqkv_w = (const float*)d_in[6];
  const float* vqkv_b = (const float*)d_in[7];
  const float* aqkv_w = (const float*)d_in[8];
  const float* aqkv_b = (const float*)d_in[9];
  const float* vproj_w = (const float*)d_in[10];
  const float* vproj_b = (const float*)d_in[11];
  const float* aproj_w = (const float*)d_in[12];
  const float* aproj_b = (const float*)d_in[13];

  float* out_v = (float*)d_out;
  float* out_a = out_v + (size_t)4 * 16 * 768 * 16 * 16;

  char* ws = (char*)d_ws;
  size_t off = 0;
  auto carve = [&](size_t bytes) {
    char* p = ws + off;
    off += (bytes + 255) & ~(size_t)255;
    return p;
  };
  float* part = (float*)carve(2560 * 2 * 4);
  ushort_t* Xv = (ushort_t*)carve((size_t)16384 * 768 * 2);
  ushort_t* Xa = (ushort_t*)carve((size_t)4096 * 768 * 2);
  ushort_t* Wqv = (ushort_t*)carve((size_t)2304 * 768 * 2);
  ushort_t* Wqa = (ushort_t*)carve((size_t)2304 * 768 * 2);
  ushort_t* Wpv = (ushort_t*)carve((size_t)768 * 768 * 2);
  ushort_t* Wpa = (ushort_t*)carve((size_t)768 * 768 * 2);
  ushort_t* Qv = (ushort_t*)carve((size_t)16384 * 768 * 2);
  ushort_t* Kv = (ushort_t*)carve((size_t)16384 * 768 * 2);
  ushort_t* Vv = (ushort_t*)carve((size_t)16384 * 768 * 2);
  ushort_t* Qa = (ushort_t*)carve((size_t)4096 * 768 * 2);
  ushort_t* Ka = (ushort_t*)carve((size_t)4096 * 768 * 2);
  ushort_t* Va = (ushort_t*)carve((size_t)4096 * 768 * 2);
  ushort_t* Ov = Xv;  // alias: X no longer needed after QKV GEMM
  ushort_t* Oa = Xa;

  fused_pre_kernel<<<3584, 256, 0, stream>>>(video, audio, part,
                                             vqkv_w, aqkv_w, vproj_w, aproj_w,
                                             Wqv, Wqa, Wpv, Wpa);
  norm_fused_kernel<<<1920, 256, 0, stream>>>(video, audio, part,
                                              vn_s, vn_b, an_s, an_b, Xv, Xa);
  qkv_fused_kernel<<<2880, 256, 0, stream>>>(Xv, Xa, Wqv, Wqa, vqkv_b, aqkv_b,
                                             Qv, Kv, Vv, Qa, Ka, Va);
  attn_fused_kernel<<<3840, 256, 0, stream>>>(Qv, Ka, Va, Ov, Qa, Kv, Vv, Oa);
  proj_fused_kernel<<<960, 256, 0, stream>>>(Ov, Oa, Wpv, Wpa, vproj_b, aproj_b,
                                             out_v, video, out_a, audio);
}

// Round 8
// 373.039 us; speedup vs baseline: 1.8906x; 1.2310x over previous
//
#include <hip/hip_runtime.h>
#include <hip/hip_bf16.h>

typedef unsigned short ushort_t;
typedef __attribute__((ext_vector_type(8))) short short8;
typedef __attribute__((ext_vector_type(4))) float f32x4;

#define DI __device__ __forceinline__

DI float b2f(unsigned int u16) {
  union { unsigned int i; float f; } v;
  v.i = u16 << 16;
  return v.f;
}
DI ushort_t f2b(float f) {
  union { float f; unsigned int u; } v; v.f = f;
  unsigned int r = v.u + 0x7FFFu + ((v.u >> 16) & 1u);
  return (ushort_t)(r >> 16);
}

// async global->LDS 16B copy: LDS dest is wave-uniform base + lane*16
DI void gl_lds16(const ushort_t* g, ushort_t* l) {
  __builtin_amdgcn_global_load_lds(
      (const __attribute__((address_space(1))) unsigned int*)g,
      (__attribute__((address_space(3))) unsigned int*)l, 16, 0, 0);
}

// ---------------------------------------------------------------------------
// Fused: GroupNorm partial stats (blocks 0..2559) + weight bf16 cvt (2560..3583)
// ---------------------------------------------------------------------------
__global__ __launch_bounds__(256) void fused_pre_kernel(
    const float* __restrict__ video, const float* __restrict__ audio,
    float* __restrict__ part,
    const float* __restrict__ w0, const float* __restrict__ w1,
    const float* __restrict__ w2, const float* __restrict__ w3,
    ushort_t* __restrict__ o0, ushort_t* __restrict__ o1,
    ushort_t* __restrict__ o2, ushort_t* __restrict__ o3) {
  const int bid = blockIdx.x;
  const int tid = threadIdx.x;
  __shared__ float red[8];
  if (bid < 2560) {
    float s = 0.f, ss = 0.f;
    if (bid < 2048) {
      int bg = bid >> 4, f = bid & 15;
      int b = bg >> 5, g = bg & 31;
      const float* base = video + ((size_t)((b * 16 + f) * 768 + g * 24)) * 256 + tid;
#pragma unroll
      for (int cl = 0; cl < 24; ++cl) {
        float v = base[cl * 256];
        s += v; ss += v * v;
      }
    } else {
      int a = bid - 2048;
      int bg = a >> 2, p = a & 3;
      int b = bg >> 5, g = bg & 31;
      const float* base = audio + ((size_t)(b * 768 + g * 24)) * 1024 + p * 256 + tid;
#pragma unroll
      for (int cl = 0; cl < 24; ++cl) {
        float v = base[cl * 1024];
        s += v; ss += v * v;
      }
    }
    for (int off = 32; off > 0; off >>= 1) { s += __shfl_down(s, off, 64); ss += __shfl_down(ss, off, 64); }
    int wv = tid >> 6, ln = tid & 63;
    if (ln == 0) { red[wv * 2] = s; red[wv * 2 + 1] = ss; }
    __syncthreads();
    if (tid == 0) {
      part[bid * 2] = red[0] + red[2] + red[4] + red[6];
      part[bid * 2 + 1] = red[1] + red[3] + red[5] + red[7];
    }
  } else {
    const int n1 = 2304 * 768, n3 = 768 * 768;
    const int total = 2 * n1 + 2 * n3;
    int wb = bid - 2560;
    for (int i = wb * 256 + tid; i < total; i += 1024 * 256) {
      if (i < n1) o0[i] = f2b(w0[i]);
      else if (i < 2 * n1) o1[i - n1] = f2b(w1[i - n1]);
      else if (i < 2 * n1 + n3) o2[i - 2 * n1] = f2b(w2[i - 2 * n1]);
      else o3[i - 2 * n1 - n3] = f2b(w3[i - 2 * n1 - n3]);
    }
  }
}

// ---------------------------------------------------------------------------
// Fused normalize (gn_final folded in: per-block channel stats from `part`).
// Blocks 0..1535: video -> Xv[n][c]; 1536..1919: audio -> Xa[n][c].
// ---------------------------------------------------------------------------
__global__ __launch_bounds__(256) void norm_fused_kernel(
    const float* __restrict__ video, const float* __restrict__ audio,
    const float* __restrict__ part,
    const float* __restrict__ vsc, const float* __restrict__ vbi,
    const float* __restrict__ asc, const float* __restrict__ abi,
    ushort_t* __restrict__ Xv, ushort_t* __restrict__ Xa) {
  __shared__ float T[32][257];
  __shared__ float shm[32], shr[32];
  const int bx = blockIdx.x;
  const int tid = threadIdx.x;
  if (bx < 1536) {
    const int bf = bx / 24, ct = bx % 24;
    const int b = bf >> 4, f = bf & 15;
    const int c0 = ct * 32;
    if (tid < 32) {
      int c = c0 + tid, g = c / 24;
      float s = 0.f, ss = 0.f;
#pragma unroll
      for (int i = 0; i < 16; ++i) {
        s += part[((b * 32 + g) * 16 + i) * 2];
        ss += part[((b * 32 + g) * 16 + i) * 2 + 1];
      }
      const float N = 24.f * 4096.f;
      float m = s / N;
      shm[tid] = m;
      shr[tid] = rsqrtf(ss / N - m * m + 1e-5f);
    }
    __syncthreads();
    for (int i = 0; i < 32; ++i) {
      int c = c0 + i;
      float v = video[((size_t)((b * 16 + f) * 768 + c)) * 256 + tid];
      T[i][tid] = (v - shm[i]) * shr[i] * vsc[c] + vbi[c];
    }
    __syncthreads();
    for (int i = 0; i < 32; ++i) {
      int id = i * 256 + tid;
      int c = id & 31, hw = id >> 5;
      Xv[((size_t)(b * 4096 + f * 256 + hw)) * 768 + c0 + c] = f2b(T[c][hw]);
    }
  } else {
    const int ax = bx - 1536;
    const int bt = ax / 24, ct = ax % 24;
    const int b = bt >> 2, t0 = (bt & 3) * 256;
    const int c0 = ct * 32;
    if (tid < 32) {
      int c = c0 + tid, g = c / 24;
      float s = 0.f, ss = 0.f;
#pragma unroll
      for (int i = 0; i < 4; ++i) {
        s += part[(2048 + (b * 32 + g) * 4 + i) * 2];
        ss += part[(2048 + (b * 32 + g) * 4 + i) * 2 + 1];
      }
      const float N = 24.f * 1024.f;
      float m = s / N;
      shm[tid] = m;
      shr[tid] = rsqrtf(ss / N - m * m + 1e-5f);
    }
    __syncthreads();
    for (int i = 0; i < 32; ++i) {
      int c = c0 + i;
      float v = audio[((size_t)(b * 768 + c)) * 1024 + t0 + tid];
      T[i][tid] = (v - shm[i]) * shr[i] * asc[c] + abi[c];
    }
    __syncthreads();
    for (int i = 0; i < 32; ++i) {
      int id = i * 256 + tid;
      int c = id & 31, tt = id >> 5;
      Xa[((size_t)(b * 1024 + t0 + tt)) * 768 + c0 + c] = f2b(T[c][tt]);
    }
  }
}

// ---------------------------------------------------------------------------
// Fused QKV GEMM (video blocks 0..2303, audio 2304..2879).
// 128x128 tile, 2-phase dbuf gl_lds16 staging, XOR chunk swizzle both sides,
// segment-local XCD bijective block swizzle.
// Q section pre-scaled by 0.125*log2(e): attention softmax runs in exp2 domain.
// ---------------------------------------------------------------------------
__global__ __launch_bounds__(256) void qkv_fused_kernel(
    const ushort_t* __restrict__ Xv, const ushort_t* __restrict__ Xa,
    const ushort_t* __restrict__ Wqv, const ushort_t* __restrict__ Wqa,
    const float* __restrict__ vqkv_b, const float* __restrict__ aqkv_b,
    ushort_t* __restrict__ Qv, ushort_t* __restrict__ Kv, ushort_t* __restrict__ Vv,
    ushort_t* __restrict__ Qa, ushort_t* __restrict__ Ka, ushort_t* __restrict__ Va) {
  __shared__ ushort_t sm[32768];  // 64 KiB dbuf
  const int bid = blockIdx.x;
  const int tid = threadIdx.x;
  const int lane = tid & 63, wave = tid >> 6;
  const int quad = lane >> 4, l16 = lane & 15;

  const bool isv = bid < 2304;
  const int lb = isv ? bid : bid - 2304;
  const int nwg = isv ? 2304 : 576;
  const ushort_t* A = isv ? Xv : Xa;
  const ushort_t* W = isv ? Wqv : Wqa;
  const float* bias = isv ? vqkv_b : aqkv_b;
  ushort_t* pQ = isv ? Qv : Qa;
  ushort_t* pK = isv ? Kv : Ka;
  ushort_t* pV = isv ? Vv : Va;
  const int M = isv ? 16384 : 4096;

  const int lid = (lb & 7) * (nwg >> 3) + (lb >> 3);
  const int n0 = (lid % 18) * 128, m0 = (lid / 18) * 128;
  const int wm = (wave & 1) * 64, wn = (wave >> 1) * 64;

  const int srow = wave * 32 + (lane >> 3);
  const int sq = ((lane & 7) ^ (lane >> 3)) * 8;
  const ushort_t* gA = A + (size_t)(m0 + srow) * 768 + sq;
  const ushort_t* gB = W + (size_t)(n0 + srow) * 768 + sq;

  f32x4 acc[4][4];
#pragma unroll
  for (int i = 0; i < 4; ++i)
#pragma unroll
    for (int j = 0; j < 4; ++j) acc[i][j] = (f32x4){0.f, 0.f, 0.f, 0.f};

  auto stage = [&](int kc, int cur) {
    ushort_t* lA = sm + cur * 8192 + wave * 2048;
    ushort_t* lB = sm + 16384 + cur * 8192 + wave * 2048;
#pragma unroll
    for (int i = 0; i < 4; ++i) {
      gl_lds16(gA + (size_t)i * 8 * 768 + kc, lA + i * 512);
      gl_lds16(gB + (size_t)i * 8 * 768 + kc, lB + i * 512);
    }
  };

  stage(0, 0);
  __syncthreads();
  int cur = 0;
  for (int t = 0; t < 12; ++t) {
    if (t < 11) stage((t + 1) * 64, cur ^ 1);
    const ushort_t* cA = sm + cur * 8192;
    const ushort_t* cB = sm + 16384 + cur * 8192;
#pragma unroll
    for (int ks = 0; ks < 2; ++ks) {
      short8 av[4], bv[4];
#pragma unroll
      for (int im = 0; im < 4; ++im) {
        int rr = wm + im * 16 + l16;
        av[im] = *reinterpret_cast<const short8*>(
            cA + rr * 64 + (((ks * 4 + quad) ^ (rr & 7)) * 8));
      }
#pragma unroll
      for (int in = 0; in < 4; ++in) {
        int rr = wn + in * 16 + l16;
        bv[in] = *reinterpret_cast<const short8*>(
            cB + rr * 64 + (((ks * 4 + quad) ^ (rr & 7)) * 8));
      }
#pragma unroll
      for (int im = 0; im < 4; ++im)
#pragma unroll
        for (int in = 0; in < 4; ++in)
          acc[im][in] = __builtin_amdgcn_mfma_f32_16x16x32_bf16(av[im], bv[in], acc[im][in], 0, 0, 0);
    }
    __syncthreads();
    cur ^= 1;
  }

  ushort_t* sC = sm;  // epilogue scratch [128][136] bf16
  const int section = n0 / 768;  // 0=Q 1=K 2=V
  const int obase = n0 - section * 768;
  if (section < 2) {
    // fold qk scale AND log2(e) into Q: softmax uses native exp2
    const float qs = (section == 0) ? 0.125f * 1.44269504088896340736f : 1.0f;
#pragma unroll
    for (int in = 0; in < 4; ++in) {
      int ol = wn + in * 16 + l16;
      float bv_ = bias[n0 + ol];
#pragma unroll
      for (int im = 0; im < 4; ++im)
#pragma unroll
        for (int r = 0; r < 4; ++r) {
          int row = wm + im * 16 + quad * 4 + r;
          sC[row * 136 + ol] = f2b((acc[im][in][r] + bv_) * qs);
        }
    }
    __syncthreads();
    ushort_t* dst = (section == 0) ? pQ : pK;
#pragma unroll
    for (int i = 0; i < 8; ++i) {
      int cid = i * 256 + tid;
      int row = cid >> 4, ch = cid & 15;
      *reinterpret_cast<uint4*>(dst + (size_t)(m0 + row) * 768 + obase + ch * 8) =
          *reinterpret_cast<const uint4*>(sC + row * 136 + ch * 8);
    }
  } else {
#pragma unroll
    for (int in = 0; in < 4; ++in) {
      int ol = wn + in * 16 + l16;
      float bv_ = bias[n0 + ol];
#pragma unroll
      for (int im = 0; im < 4; ++im)
#pragma unroll
        for (int r = 0; r < 4; ++r) {
          int mr = wm + im * 16 + quad * 4 + r;
          sC[ol * 136 + mr] = f2b(acc[im][in][r] + bv_);
        }
    }
    __syncthreads();
#pragma unroll
    for (int i = 0; i < 8; ++i) {
      int cid = i * 256 + tid;
      int o = cid >> 4, ch = cid & 15;
      *reinterpret_cast<uint4*>(pV + (size_t)(obase + o) * M + m0 + ch * 8) =
          *reinterpret_cast<const uint4*>(sC + o * 136 + ch * 8);
    }
  }
}

// ---------------------------------------------------------------------------
// Fused proj GEMM + residual (video blocks 0..767, audio 768..959)
// ---------------------------------------------------------------------------
__global__ __launch_bounds__(256) void proj_fused_kernel(
    const ushort_t* __restrict__ Ov, const ushort_t* __restrict__ Oa,
    const ushort_t* __restrict__ Wpv, const ushort_t* __restrict__ Wpa,
    const float* __restrict__ vproj_b, const float* __restrict__ aproj_b,
    float* __restrict__ out_v, const float* __restrict__ video,
    float* __restrict__ out_a, const float* __restrict__ audio) {
  __shared__ ushort_t sm[32768];
  const int bid = blockIdx.x;
  const int tid = threadIdx.x;
  const int lane = tid & 63, wave = tid >> 6;
  const int quad = lane >> 4, l16 = lane & 15;

  const bool isv = bid < 768;
  const int lb = isv ? bid : bid - 768;
  const int nwg = isv ? 768 : 192;
  const ushort_t* A = isv ? Ov : Oa;
  const ushort_t* W = isv ? Wpv : Wpa;
  const float* bias = isv ? vproj_b : aproj_b;
  float* outp = isv ? out_v : out_a;
  const float* resp = isv ? video : audio;

  const int lid = (lb & 7) * (nwg >> 3) + (lb >> 3);
  const int n0 = (lid % 6) * 128, m0 = (lid / 6) * 128;
  const int wm = (wave & 1) * 64, wn = (wave >> 1) * 64;

  const int srow = wave * 32 + (lane >> 3);
  const int sq = ((lane & 7) ^ (lane >> 3)) * 8;
  const ushort_t* gA = A + (size_t)(m0 + srow) * 768 + sq;
  const ushort_t* gB = W + (size_t)(n0 + srow) * 768 + sq;

  f32x4 acc[4][4];
#pragma unroll
  for (int i = 0; i < 4; ++i)
#pragma unroll
    for (int j = 0; j < 4; ++j) acc[i][j] = (f32x4){0.f, 0.f, 0.f, 0.f};

  auto stage = [&](int kc, int cur) {
    ushort_t* lA = sm + cur * 8192 + wave * 2048;
    ushort_t* lB = sm + 16384 + cur * 8192 + wave * 2048;
#pragma unroll
    for (int i = 0; i < 4; ++i) {
      gl_lds16(gA + (size_t)i * 8 * 768 + kc, lA + i * 512);
      gl_lds16(gB + (size_t)i * 8 * 768 + kc, lB + i * 512);
    }
  };

  stage(0, 0);
  __syncthreads();
  int cur = 0;
  for (int t = 0; t < 12; ++t) {
    if (t < 11) stage((t + 1) * 64, cur ^ 1);
    const ushort_t* cA = sm + cur * 8192;
    const ushort_t* cB = sm + 16384 + cur * 8192;
#pragma unroll
    for (int ks = 0; ks < 2; ++ks) {
      short8 av[4], bv[4];
#pragma unroll
      for (int im = 0; im < 4; ++im) {
        int rr = wm + im * 16 + l16;
        av[im] = *reinterpret_cast<const short8*>(
            cA + rr * 64 + (((ks * 4 + quad) ^ (rr & 7)) * 8));
      }
#pragma unroll
      for (int in = 0; in < 4; ++in) {
        int rr = wn + in * 16 + l16;
        bv[in] = *reinterpret_cast<const short8*>(
            cB + rr * 64 + (((ks * 4 + quad) ^ (rr & 7)) * 8));
      }
#pragma unroll
      for (int im = 0; im < 4; ++im)
#pragma unroll
        for (int in = 0; in < 4; ++in)
          acc[im][in] = __builtin_amdgcn_mfma_f32_16x16x32_bf16(av[im], bv[in], acc[im][in], 0, 0, 0);
    }
    __syncthreads();
    cur ^= 1;
  }

  ushort_t* sC = sm;  // [128 o][136] bf16, transposed store
#pragma unroll
  for (int in = 0; in < 4; ++in) {
    int ol = wn + in * 16 + l16;
    float bv_ = bias[n0 + ol];
#pragma unroll
    for (int im = 0; im < 4; ++im)
#pragma unroll
      for (int r = 0; r < 4; ++r) {
        int mr = wm + im * 16 + quad * 4 + r;
        sC[ol * 136 + mr] = f2b(acc[im][in][r] + bv_);
      }
  }
  __syncthreads();
#pragma unroll
  for (int i = 0; i < 16; ++i) {
    int cid = i * 256 + tid;
    int o = cid >> 5, ch = cid & 31;
    uint2 pk = *reinterpret_cast<const uint2*>(sC + o * 136 + ch * 4);
    size_t gidx;
    if (isv) {
      int b = m0 >> 12, f = (m0 >> 8) & 15, hw0 = m0 & 255;
      gidx = ((size_t)((b * 16 + f) * 768 + n0 + o)) * 256 + hw0 + ch * 4;
    } else {
      int b = m0 >> 10, t0 = m0 & 1023;
      gidx = ((size_t)(b * 768 + n0 + o)) * 1024 + t0 + ch * 4;
    }
    float4 rv = *reinterpret_cast<const float4*>(resp + gidx);
    float4 ov;
    ov.x = rv.x + b2f(pk.x & 0xffff);
    ov.y = rv.y + b2f(pk.x >> 16);
    ov.z = rv.z + b2f(pk.y & 0xffff);
    ov.w = rv.w + b2f(pk.y >> 16);
    *reinterpret_cast<float4*>(outp + gidx) = ov;
  }
}

// ---------------------------------------------------------------------------
// Fused MFMA flash attention.
// Round-8 fix: SEGMENT-LOCAL XCD swizzle. Round 7's global swizzle put all
// 768 heavy (NT=8) audio-q blocks on 2 of 8 XCDs -> 2x tail. Now each
// segment spreads over all 8 XCDs AND heavy blocks dispatch FIRST:
//   bx0 0..767    -> audio-q segment (NT=8), swz within 768 = 8*96
//   bx0 768..3839 -> video-q segment (NT=2), swz within 3072 = 8*384
// Keeps: staged LDS path, exp2-domain softmax (Q pre-scaled by log2 e),
// ones-MFMA row-sum, round-half-up P->bf16, max3 chains.
// ---------------------------------------------------------------------------
__global__ __launch_bounds__(256) void attn_fused_kernel(
    const ushort_t* __restrict__ Qv, const ushort_t* __restrict__ Ka,
    const ushort_t* __restrict__ Va, ushort_t* __restrict__ Ov,
    const ushort_t* __restrict__ Qa, const ushort_t* __restrict__ Kv,
    const ushort_t* __restrict__ Vv, ushort_t* __restrict__ Oa) {
  __shared__ ushort_t sm[37376];       // 74752 B
  ushort_t* sQ = sm;                   // [64][64]  xor8
  ushort_t* sK = sm + 4096;            // [128][64] xor8
  ushort_t* sV0 = sm + 12288;          // [64][128] xor16
  ushort_t* sV1 = sm + 20480;
  ushort_t* sP = sm + 28672;           // [64][136] P bf16 / O bounce
  const int tid = threadIdx.x;
  const int lane = tid & 63, wave = tid >> 6;
  const int quad = lane >> 4, l16 = lane & 15;

  // Segment-local XCD swizzle; heavy audio-q segment dispatched first.
  const int bx0 = blockIdx.x;
  const bool isv = bx0 >= 768;
  int lb;
  if (isv) {
    int local = bx0 - 768;             // 3072 = 8 * 384
    lb = (local & 7) * 384 + (local >> 3);
  } else {
    int local = bx0;                   // 768 = 8 * 96
    lb = (local & 7) * 96 + (local >> 3);
  }

  const ushort_t* Qt = isv ? Qv : Qa;
  const ushort_t* Kt = isv ? Ka : Kv;
  const ushort_t* Vc = isv ? Va : Vv;
  ushort_t* Ot = isv ? Ov : Oa;
  const int qlog = isv ? 4 : 2;        // NQT = 16 / 4
  const int NT = isv ? 2 : 8;          // SW/128
  const int QW = isv ? 1024 : 256;
  const int SW = isv ? 256 : 1024;
  const int TQb = isv ? 4096 : 1024;
  const int TSb = isv ? 1024 : 4096;
  const int Ms = isv ? 4096 : 16384;

  const int qt = lb & ((1 << qlog) - 1);
  const int win = (lb >> qlog) & 3;
  const int whb = lb >> (qlog + 2);
  const int h = whb % 12;
  const int batch = whb / 12;
  const int hc = h * 64;
  const int nq0 = batch * TQb + win * QW + qt * 64;
  const int ns_base = batch * TSb + win * SW;

  const int r8 = lane >> 3, c8 = lane & 7;
  const int s8 = (c8 ^ r8) * 8;
  const int r16 = lane >> 4, c16 = lane & 15;

  auto stage_k = [&](int ns0) {
#pragma unroll
    for (int i = 0; i < 4; ++i) {
      int row = wave * 32 + i * 8 + r8;
      gl_lds16(Kt + (size_t)(ns0 + row) * 768 + hc + s8, sK + (wave * 32 + i * 8) * 64);
    }
  };
  auto stage_v = [&](int ns0, ushort_t* sV) {
#pragma unroll
    for (int i = 0; i < 4; ++i) {
      int ch = wave * 16 + i * 4 + r16;
      int slot = c16 ^ (i * 4 + r16);
      gl_lds16(Vc + (size_t)(hc + ch) * Ms + ns0 + slot * 8, sV + (wave * 16 + i * 4) * 128);
    }
  };

#pragma unroll
  for (int i = 0; i < 2; ++i) {
    int row = wave * 16 + i * 8 + r8;
    gl_lds16(Qt + (size_t)(nq0 + row) * 768 + hc + s8, sQ + (wave * 16 + i * 8) * 64);
  }
  stage_k(ns_base);
  stage_v(ns_base, sV0);
  __syncthreads();

  short8 qf[2];
#pragma unroll
  for (int ks = 0; ks < 2; ++ks)
    qf[ks] = *reinterpret_cast<const short8*>(
        sQ + (wave * 16 + l16) * 64 + (((ks * 4 + quad) ^ (l16 & 7)) * 8));

  const short8 vones = {0x3F80, 0x3F80, 0x3F80, 0x3F80, 0x3F80, 0x3F80, 0x3F80, 0x3F80};

  float mr[4];
  f32x4 on[4], onl;
#pragma unroll
  for (int r = 0; r < 4; ++r) mr[r] = -1e30f;
#pragma unroll
  for (int nc = 0; nc < 4; ++nc) on[nc] = (f32x4){0.f, 0.f, 0.f, 0.f};
  onl = (f32x4){0.f, 0.f, 0.f, 0.f};
  const int prow0 = (wave * 16 + quad * 4) * 136;

  for (int t = 0; t < NT; ++t) {
    if (t + 1 < NT) stage_v(ns_base + (t + 1) * 128, (t & 1) ? sV0 : sV1);
    f32x4 sf[8];
#pragma unroll
    for (int nt = 0; nt < 8; ++nt) sf[nt] = (f32x4){0.f, 0.f, 0.f, 0.f};
#pragma unroll
    for (int ks = 0; ks < 2; ++ks) {
#pragma unroll
      for (int nt = 0; nt < 8; ++nt) {
        short8 kf = *reinterpret_cast<const short8*>(
            sK + (nt * 16 + l16) * 64 + (((ks * 4 + quad) ^ (l16 & 7)) * 8));
        sf[nt] = __builtin_amdgcn_mfma_f32_16x16x32_bf16(qf[ks], kf, sf[nt], 0, 0, 0);
      }
    }
    __syncthreads();
    if (t + 1 < NT) stage_k(ns_base + (t + 1) * 128);
    // ---- online softmax in exp2 domain; row-sum deferred to ones-MFMA
#pragma unroll
    for (int r = 0; r < 4; ++r) {
      float m_ = fmaxf(fmaxf(sf[0][r], sf[1][r]), sf[2][r]);
      m_ = fmaxf(fmaxf(m_, sf[3][r]), sf[4][r]);
      m_ = fmaxf(fmaxf(m_, sf[5][r]), sf[6][r]);
      m_ = fmaxf(m_, sf[7][r]);
#pragma unroll
      for (int off = 1; off < 16; off <<= 1) m_ = fmaxf(m_, __shfl_xor(m_, off));
      float mnew = fmaxf(mr[r], m_);
      float al = __builtin_amdgcn_exp2f(mr[r] - mnew);
      mr[r] = mnew;
      int prow = prow0 + r * 136;
#pragma unroll
      for (int nt = 0; nt < 8; ++nt) {
        float p = __builtin_amdgcn_exp2f(sf[nt][r] - mnew);
        sP[prow + nt * 16 + l16] = (ushort_t)((__float_as_uint(p) + 0x8000u) >> 16);
      }
#pragma unroll
      for (int nc = 0; nc < 4; ++nc) on[nc][r] *= al;
      onl[r] *= al;
    }
    // ---- O += P V ; l += P 1 (5th ones-MFMA replaces shuffle-add row-sum)
    const ushort_t* sV = (t & 1) ? sV1 : sV0;
#pragma unroll
    for (int ks = 0; ks < 4; ++ks) {
      short8 pf = *reinterpret_cast<const short8*>(sP + (wave * 16 + l16) * 136 + ks * 32 + quad * 8);
#pragma unroll
      for (int nc = 0; nc < 4; ++nc) {
        short8 vf = *reinterpret_cast<const short8*>(
            sV + (nc * 16 + l16) * 128 + (((ks * 4 + quad) ^ l16) * 8));
        on[nc] = __builtin_amdgcn_mfma_f32_16x16x32_bf16(pf, vf, on[nc], 0, 0, 0);
      }
      onl = __builtin_amdgcn_mfma_f32_16x16x32_bf16(pf, vones, onl, 0, 0, 0);
    }
    if (t + 1 < NT) __syncthreads();
  }
#pragma unroll
  for (int r = 0; r < 4; ++r) {
    float inv = 1.f / onl[r];
    int prow = prow0 + r * 136;
#pragma unroll
    for (int nc = 0; nc < 4; ++nc)
      sP[prow + nc * 16 + l16] = f2b(on[nc][r] * inv);
  }
  __syncthreads();
#pragma unroll
  for (int i = 0; i < 2; ++i) {
    int c = i * 256 + tid;
    int row = c >> 3, cc = c & 7;
    *reinterpret_cast<uint4*>(Ot + (size_t)(nq0 + row) * 768 + hc + cc * 8) =
        *reinterpret_cast<const uint4*>(sP + row * 136 + cc * 8);
  }
}

// ---------------------------------------------------------------------------
extern "C" void kernel_launch(void* const* d_in, const int* in_sizes, int n_in,
                              void* d_out, int out_size, void* d_ws, size_t ws_size,
                              hipStream_t stream) {
  (void)in_sizes; (void)n_in; (void)out_size; (void)ws_size;
  const float* video = (const float*)d_in[0];
  const float* audio = (const float*)d_in[1];
  const float* vn_s = (const float*)d_in[2];
  const float* vn_b = (const float*)d_in[3];
  const float* an_s = (const float*)d_in[4];
  const float* an_b = (const float*)d_in[5];
  const float* vqkv_w = (const float*)d_in[6];
  const float* vqkv_b = (const float*)d_in[7];
  const float* aqkv_w = (const float*)d_in[8];
  const float* aqkv_b = (const float*)d_in[9];
  const float* vproj_w = (const float*)d_in[10];
  const float* vproj_b = (const float*)d_in[11];
  const float* aproj_w = (const float*)d_in[12];
  const float* aproj_b = (const float*)d_in[13];

  float* out_v = (float*)d_out;
  float* out_a = out_v + (size_t)4 * 16 * 768 * 16 * 16;

  char* ws = (char*)d_ws;
  size_t off = 0;
  auto carve = [&](size_t bytes) {
    char* p = ws + off;
    off += (bytes + 255) & ~(size_t)255;
    return p;
  };
  float* part = (float*)carve(2560 * 2 * 4);
  ushort_t* Xv = (ushort_t*)carve((size_t)16384 * 768 * 2);
  ushort_t* Xa = (ushort_t*)carve((size_t)4096 * 768 * 2);
  ushort_t* Wqv = (ushort_t*)carve((size_t)2304 * 768 * 2);
  ushort_t* Wqa = (ushort_t*)carve((size_t)2304 * 768 * 2);
  ushort_t* Wpv = (ushort_t*)carve((size_t)768 * 768 * 2);
  ushort_t* Wpa = (ushort_t*)carve((size_t)768 * 768 * 2);
  ushort_t* Qv = (ushort_t*)carve((size_t)16384 * 768 * 2);
  ushort_t* Kv = (ushort_t*)carve((size_t)16384 * 768 * 2);
  ushort_t* Vv = (ushort_t*)carve((size_t)16384 * 768 * 2);
  ushort_t* Qa = (ushort_t*)carve((size_t)4096 * 768 * 2);
  ushort_t* Ka = (ushort_t*)carve((size_t)4096 * 768 * 2);
  ushort_t* Va = (ushort_t*)carve((size_t)4096 * 768 * 2);
  ushort_t* Ov = Xv;  // alias: X no longer needed after QKV GEMM
  ushort_t* Oa = Xa;

  fused_pre_kernel<<<3584, 256, 0, stream>>>(video, audio, part,
                                             vqkv_w, aqkv_w, vproj_w, aproj_w,
                                             Wqv, Wqa, Wpv, Wpa);
  norm_fused_kernel<<<1920, 256, 0, stream>>>(video, audio, part,
                                              vn_s, vn_b, an_s, an_b, Xv, Xa);
  qkv_fused_kernel<<<2880, 256, 0, stream>>>(Xv, Xa, Wqv, Wqa, vqkv_b, aqkv_b,
                                             Qv, Kv, Vv, Qa, Ka, Va);
  attn_fused_kernel<<<3840, 256, 0, stream>>>(Qv, Ka, Va, Ov, Qa, Kv, Vv, Oa);
  proj_fused_kernel<<<960, 256, 0, stream>>>(Ov, Oa, Wpv, Wpa, vproj_b, aproj_b,
                                             out_v, video, out_a, audio);
}

// Round 9
// 334.886 us; speedup vs baseline: 2.1060x; 1.1139x over previous
//
#include <hip/hip_runtime.h>
#include <hip/hip_bf16.h>

typedef unsigned short ushort_t;
typedef __attribute__((ext_vector_type(8))) short short8;
typedef __attribute__((ext_vector_type(4))) float f32x4;
struct __align__(8) us4 { ushort_t x, y, z, w; };

#define DI __device__ __forceinline__

DI float b2f(unsigned int u16) {
  union { unsigned int i; float f; } v;
  v.i = u16 << 16;
  return v.f;
}
DI ushort_t f2b(float f) {
  union { float f; unsigned int u; } v; v.f = f;
  unsigned int r = v.u + 0x7FFFu + ((v.u >> 16) & 1u);
  return (ushort_t)(r >> 16);
}

// async global->LDS 16B copy: LDS dest is wave-uniform base + lane*16
DI void gl_lds16(const ushort_t* g, ushort_t* l) {
  __builtin_amdgcn_global_load_lds(
      (const __attribute__((address_space(1))) unsigned int*)g,
      (__attribute__((address_space(3))) unsigned int*)l, 16, 0, 0);
}

// ---------------------------------------------------------------------------
// Fused: GroupNorm partial stats (blocks 0..2559) + weight bf16 cvt (2560..3583)
// All loads float4 (16B/lane); wcvt emits ushort4 (8B/lane).
// ---------------------------------------------------------------------------
__global__ __launch_bounds__(256) void fused_pre_kernel(
    const float* __restrict__ video, const float* __restrict__ audio,
    float* __restrict__ part,
    const float* __restrict__ w0, const float* __restrict__ w1,
    const float* __restrict__ w2, const float* __restrict__ w3,
    ushort_t* __restrict__ o0, ushort_t* __restrict__ o1,
    ushort_t* __restrict__ o2, ushort_t* __restrict__ o3) {
  const int bid = blockIdx.x;
  const int tid = threadIdx.x;
  __shared__ float red[8];
  if (bid < 2560) {
    float s = 0.f, ss = 0.f;
    if (bid < 2048) {
      int bg = bid >> 4, f = bid & 15;
      int b = bg >> 5, g = bg & 31;
      // 24ch x 256hw slab is 6144 contiguous floats = 1536 float4
      const float4* base = reinterpret_cast<const float4*>(
          video + ((size_t)((b * 16 + f) * 768 + g * 24)) * 256);
#pragma unroll
      for (int i = 0; i < 6; ++i) {
        float4 v = base[i * 256 + tid];
        s += v.x + v.y + v.z + v.w;
        ss += v.x * v.x + v.y * v.y + v.z * v.z + v.w * v.w;
      }
    } else {
      int a = bid - 2048;
      int bg = a >> 2, p = a & 3;
      int b = bg >> 5, g = bg & 31;
      // 24 rows (stride 1024), 256 floats each: 4 rows/pass x 64 float4
      const float* ab = audio + ((size_t)(b * 768 + g * 24)) * 1024 + p * 256;
#pragma unroll
      for (int i = 0; i < 6; ++i) {
        int row = i * 4 + (tid >> 6);
        float4 v = *reinterpret_cast<const float4*>(ab + (size_t)row * 1024 + (tid & 63) * 4);
        s += v.x + v.y + v.z + v.w;
        ss += v.x * v.x + v.y * v.y + v.z * v.z + v.w * v.w;
      }
    }
    for (int off = 32; off > 0; off >>= 1) { s += __shfl_down(s, off, 64); ss += __shfl_down(ss, off, 64); }
    int wv = tid >> 6, ln = tid & 63;
    if (ln == 0) { red[wv * 2] = s; red[wv * 2 + 1] = ss; }
    __syncthreads();
    if (tid == 0) {
      part[bid * 2] = red[0] + red[2] + red[4] + red[6];
      part[bid * 2 + 1] = red[1] + red[3] + red[5] + red[7];
    }
  } else {
    // weight cvt in float4 -> ushort4 units
    const int n1 = (2304 * 768) / 4, n3 = (768 * 768) / 4;
    const int total = 2 * n1 + 2 * n3;
    int wb = bid - 2560;
    for (int i = wb * 256 + tid; i < total; i += 1024 * 256) {
      const float4* src;
      ushort_t* dst;
      int j;
      if (i < n1) { src = (const float4*)w0; dst = o0; j = i; }
      else if (i < 2 * n1) { src = (const float4*)w1; dst = o1; j = i - n1; }
      else if (i < 2 * n1 + n3) { src = (const float4*)w2; dst = o2; j = i - 2 * n1; }
      else { src = (const float4*)w3; dst = o3; j = i - 2 * n1 - n3; }
      float4 v = src[j];
      us4 o = {f2b(v.x), f2b(v.y), f2b(v.z), f2b(v.w)};
      *reinterpret_cast<us4*>(dst + (size_t)j * 4) = o;
    }
  }
}

// ---------------------------------------------------------------------------
// Fused normalize (gn_final folded in: per-block channel stats from `part`).
// Blocks 0..1535: video -> Xv[n][c]; 1536..1919: audio -> Xa[n][c].
// float4 loads (one wave = one full 1KB row), ushort4 stores (4 ch/lane).
// ---------------------------------------------------------------------------
__global__ __launch_bounds__(256) void norm_fused_kernel(
    const float* __restrict__ video, const float* __restrict__ audio,
    const float* __restrict__ part,
    const float* __restrict__ vsc, const float* __restrict__ vbi,
    const float* __restrict__ asc, const float* __restrict__ abi,
    ushort_t* __restrict__ Xv, ushort_t* __restrict__ Xa) {
  __shared__ float T[32][257];
  __shared__ float shA[32], shB[32];  // per-channel scale/shift: y = A*x + B
  const int bx = blockIdx.x;
  const int tid = threadIdx.x;
  if (bx < 1536) {
    const int bf = bx / 24, ct = bx % 24;
    const int b = bf >> 4, f = bf & 15;
    const int c0 = ct * 32;
    if (tid < 32) {
      int c = c0 + tid, g = c / 24;
      float s = 0.f, ss = 0.f;
#pragma unroll
      for (int i = 0; i < 16; ++i) {
        s += part[((b * 32 + g) * 16 + i) * 2];
        ss += part[((b * 32 + g) * 16 + i) * 2 + 1];
      }
      const float N = 24.f * 4096.f;
      float m = s / N;
      float r = rsqrtf(ss / N - m * m + 1e-5f);
      float A = r * vsc[c];
      shA[tid] = A;
      shB[tid] = vbi[c] - m * A;
    }
    __syncthreads();
    // load+normalize: 32 rows x 64 float4; one wave covers one row per iter
#pragma unroll
    for (int i = 0; i < 8; ++i) {
      int idx = i * 256 + tid;
      int c = idx >> 6, q4 = idx & 63;
      float4 v = *reinterpret_cast<const float4*>(
          video + ((size_t)((b * 16 + f) * 768 + c0 + c)) * 256 + q4 * 4);
      float A = shA[c], B = shB[c];
      float4 o = {A * v.x + B, A * v.y + B, A * v.z + B, A * v.w + B};
      *reinterpret_cast<float4*>(&T[c][q4 * 4]) = o;
    }
    __syncthreads();
    // store token-major: 256 hw x 8 ch-quads; ushort4 per lane
#pragma unroll
    for (int i = 0; i < 8; ++i) {
      int idx = i * 256 + tid;
      int c4 = idx & 7, hw = idx >> 3;
      us4 o = {f2b(T[c4 * 4 + 0][hw]), f2b(T[c4 * 4 + 1][hw]),
               f2b(T[c4 * 4 + 2][hw]), f2b(T[c4 * 4 + 3][hw])};
      *reinterpret_cast<us4*>(Xv + ((size_t)(b * 4096 + f * 256 + hw)) * 768 + c0 + c4 * 4) = o;
    }
  } else {
    const int ax = bx - 1536;
    const int bt = ax / 24, ct = ax % 24;
    const int b = bt >> 2, t0 = (bt & 3) * 256;
    const int c0 = ct * 32;
    if (tid < 32) {
      int c = c0 + tid, g = c / 24;
      float s = 0.f, ss = 0.f;
#pragma unroll
      for (int i = 0; i < 4; ++i) {
        s += part[(2048 + (b * 32 + g) * 4 + i) * 2];
        ss += part[(2048 + (b * 32 + g) * 4 + i) * 2 + 1];
      }
      const float N = 24.f * 1024.f;
      float m = s / N;
      float r = rsqrtf(ss / N - m * m + 1e-5f);
      float A = r * asc[c];
      shA[tid] = A;
      shB[tid] = abi[c] - m * A;
    }
    __syncthreads();
#pragma unroll
    for (int i = 0; i < 8; ++i) {
      int idx = i * 256 + tid;
      int c = idx >> 6, q4 = idx & 63;
      float4 v = *reinterpret_cast<const float4*>(
          audio + ((size_t)(b * 768 + c0 + c)) * 1024 + t0 + q4 * 4);
      float A = shA[c], B = shB[c];
      float4 o = {A * v.x + B, A * v.y + B, A * v.z + B, A * v.w + B};
      *reinterpret_cast<float4*>(&T[c][q4 * 4]) = o;
    }
    __syncthreads();
#pragma unroll
    for (int i = 0; i < 8; ++i) {
      int idx = i * 256 + tid;
      int c4 = idx & 7, tt = idx >> 3;
      us4 o = {f2b(T[c4 * 4 + 0][tt]), f2b(T[c4 * 4 + 1][tt]),
               f2b(T[c4 * 4 + 2][tt]), f2b(T[c4 * 4 + 3][tt])};
      *reinterpret_cast<us4*>(Xa + ((size_t)(b * 1024 + t0 + tt)) * 768 + c0 + c4 * 4) = o;
    }
  }
}

// ---------------------------------------------------------------------------
// Fused QKV GEMM (video blocks 0..2303, audio 2304..2879).
// 128x128 tile, 2-phase dbuf gl_lds16 staging, XOR chunk swizzle both sides,
// segment-local XCD bijective block swizzle.
// Q section pre-scaled by 0.125*log2(e): attention softmax runs in exp2 domain.
// ---------------------------------------------------------------------------
__global__ __launch_bounds__(256) void qkv_fused_kernel(
    const ushort_t* __restrict__ Xv, const ushort_t* __restrict__ Xa,
    const ushort_t* __restrict__ Wqv, const ushort_t* __restrict__ Wqa,
    const float* __restrict__ vqkv_b, const float* __restrict__ aqkv_b,
    ushort_t* __restrict__ Qv, ushort_t* __restrict__ Kv, ushort_t* __restrict__ Vv,
    ushort_t* __restrict__ Qa, ushort_t* __restrict__ Ka, ushort_t* __restrict__ Va) {
  __shared__ ushort_t sm[32768];  // 64 KiB dbuf
  const int bid = blockIdx.x;
  const int tid = threadIdx.x;
  const int lane = tid & 63, wave = tid >> 6;
  const int quad = lane >> 4, l16 = lane & 15;

  const bool isv = bid < 2304;
  const int lb = isv ? bid : bid - 2304;
  const int nwg = isv ? 2304 : 576;
  const ushort_t* A = isv ? Xv : Xa;
  const ushort_t* W = isv ? Wqv : Wqa;
  const float* bias = isv ? vqkv_b : aqkv_b;
  ushort_t* pQ = isv ? Qv : Qa;
  ushort_t* pK = isv ? Kv : Ka;
  ushort_t* pV = isv ? Vv : Va;
  const int M = isv ? 16384 : 4096;

  const int lid = (lb & 7) * (nwg >> 3) + (lb >> 3);
  const int n0 = (lid % 18) * 128, m0 = (lid / 18) * 128;
  const int wm = (wave & 1) * 64, wn = (wave >> 1) * 64;

  const int srow = wave * 32 + (lane >> 3);
  const int sq = ((lane & 7) ^ (lane >> 3)) * 8;
  const ushort_t* gA = A + (size_t)(m0 + srow) * 768 + sq;
  const ushort_t* gB = W + (size_t)(n0 + srow) * 768 + sq;

  f32x4 acc[4][4];
#pragma unroll
  for (int i = 0; i < 4; ++i)
#pragma unroll
    for (int j = 0; j < 4; ++j) acc[i][j] = (f32x4){0.f, 0.f, 0.f, 0.f};

  auto stage = [&](int kc, int cur) {
    ushort_t* lA = sm + cur * 8192 + wave * 2048;
    ushort_t* lB = sm + 16384 + cur * 8192 + wave * 2048;
#pragma unroll
    for (int i = 0; i < 4; ++i) {
      gl_lds16(gA + (size_t)i * 8 * 768 + kc, lA + i * 512);
      gl_lds16(gB + (size_t)i * 8 * 768 + kc, lB + i * 512);
    }
  };

  stage(0, 0);
  __syncthreads();
  int cur = 0;
  for (int t = 0; t < 12; ++t) {
    if (t < 11) stage((t + 1) * 64, cur ^ 1);
    const ushort_t* cA = sm + cur * 8192;
    const ushort_t* cB = sm + 16384 + cur * 8192;
#pragma unroll
    for (int ks = 0; ks < 2; ++ks) {
      short8 av[4], bv[4];
#pragma unroll
      for (int im = 0; im < 4; ++im) {
        int rr = wm + im * 16 + l16;
        av[im] = *reinterpret_cast<const short8*>(
            cA + rr * 64 + (((ks * 4 + quad) ^ (rr & 7)) * 8));
      }
#pragma unroll
      for (int in = 0; in < 4; ++in) {
        int rr = wn + in * 16 + l16;
        bv[in] = *reinterpret_cast<const short8*>(
            cB + rr * 64 + (((ks * 4 + quad) ^ (rr & 7)) * 8));
      }
#pragma unroll
      for (int im = 0; im < 4; ++im)
#pragma unroll
        for (int in = 0; in < 4; ++in)
          acc[im][in] = __builtin_amdgcn_mfma_f32_16x16x32_bf16(av[im], bv[in], acc[im][in], 0, 0, 0);
    }
    __syncthreads();
    cur ^= 1;
  }

  ushort_t* sC = sm;  // epilogue scratch [128][136] bf16
  const int section = n0 / 768;  // 0=Q 1=K 2=V
  const int obase = n0 - section * 768;
  if (section < 2) {
    // fold qk scale AND log2(e) into Q: softmax uses native exp2
    const float qs = (section == 0) ? 0.125f * 1.44269504088896340736f : 1.0f;
#pragma unroll
    for (int in = 0; in < 4; ++in) {
      int ol = wn + in * 16 + l16;
      float bv_ = bias[n0 + ol];
#pragma unroll
      for (int im = 0; im < 4; ++im)
#pragma unroll
        for (int r = 0; r < 4; ++r) {
          int row = wm + im * 16 + quad * 4 + r;
          sC[row * 136 + ol] = f2b((acc[im][in][r] + bv_) * qs);
        }
    }
    __syncthreads();
    ushort_t* dst = (section == 0) ? pQ : pK;
#pragma unroll
    for (int i = 0; i < 8; ++i) {
      int cid = i * 256 + tid;
      int row = cid >> 4, ch = cid & 15;
      *reinterpret_cast<uint4*>(dst + (size_t)(m0 + row) * 768 + obase + ch * 8) =
          *reinterpret_cast<const uint4*>(sC + row * 136 + ch * 8);
    }
  } else {
#pragma unroll
    for (int in = 0; in < 4; ++in) {
      int ol = wn + in * 16 + l16;
      float bv_ = bias[n0 + ol];
#pragma unroll
      for (int im = 0; im < 4; ++im)
#pragma unroll
        for (int r = 0; r < 4; ++r) {
          int mr = wm + im * 16 + quad * 4 + r;
          sC[ol * 136 + mr] = f2b(acc[im][in][r] + bv_);
        }
    }
    __syncthreads();
#pragma unroll
    for (int i = 0; i < 8; ++i) {
      int cid = i * 256 + tid;
      int o = cid >> 4, ch = cid & 15;
      *reinterpret_cast<uint4*>(pV + (size_t)(obase + o) * M + m0 + ch * 8) =
          *reinterpret_cast<const uint4*>(sC + o * 136 + ch * 8);
    }
  }
}

// ---------------------------------------------------------------------------
// Fused proj GEMM + residual (video blocks 0..767, audio 768..959)
// ---------------------------------------------------------------------------
__global__ __launch_bounds__(256) void proj_fused_kernel(
    const ushort_t* __restrict__ Ov, const ushort_t* __restrict__ Oa,
    const ushort_t* __restrict__ Wpv, const ushort_t* __restrict__ Wpa,
    const float* __restrict__ vproj_b, const float* __restrict__ aproj_b,
    float* __restrict__ out_v, const float* __restrict__ video,
    float* __restrict__ out_a, const float* __restrict__ audio) {
  __shared__ ushort_t sm[32768];
  const int bid = blockIdx.x;
  const int tid = threadIdx.x;
  const int lane = tid & 63, wave = tid >> 6;
  const int quad = lane >> 4, l16 = lane & 15;

  const bool isv = bid < 768;
  const int lb = isv ? bid : bid - 768;
  const int nwg = isv ? 768 : 192;
  const ushort_t* A = isv ? Ov : Oa;
  const ushort_t* W = isv ? Wpv : Wpa;
  const float* bias = isv ? vproj_b : aproj_b;
  float* outp = isv ? out_v : out_a;
  const float* resp = isv ? video : audio;

  const int lid = (lb & 7) * (nwg >> 3) + (lb >> 3);
  const int n0 = (lid % 6) * 128, m0 = (lid / 6) * 128;
  const int wm = (wave & 1) * 64, wn = (wave >> 1) * 64;

  const int srow = wave * 32 + (lane >> 3);
  const int sq = ((lane & 7) ^ (lane >> 3)) * 8;
  const ushort_t* gA = A + (size_t)(m0 + srow) * 768 + sq;
  const ushort_t* gB = W + (size_t)(n0 + srow) * 768 + sq;

  f32x4 acc[4][4];
#pragma unroll
  for (int i = 0; i < 4; ++i)
#pragma unroll
    for (int j = 0; j < 4; ++j) acc[i][j] = (f32x4){0.f, 0.f, 0.f, 0.f};

  auto stage = [&](int kc, int cur) {
    ushort_t* lA = sm + cur * 8192 + wave * 2048;
    ushort_t* lB = sm + 16384 + cur * 8192 + wave * 2048;
#pragma unroll
    for (int i = 0; i < 4; ++i) {
      gl_lds16(gA + (size_t)i * 8 * 768 + kc, lA + i * 512);
      gl_lds16(gB + (size_t)i * 8 * 768 + kc, lB + i * 512);
    }
  };

  stage(0, 0);
  __syncthreads();
  int cur = 0;
  for (int t = 0; t < 12; ++t) {
    if (t < 11) stage((t + 1) * 64, cur ^ 1);
    const ushort_t* cA = sm + cur * 8192;
    const ushort_t* cB = sm + 16384 + cur * 8192;
#pragma unroll
    for (int ks = 0; ks < 2; ++ks) {
      short8 av[4], bv[4];
#pragma unroll
      for (int im = 0; im < 4; ++im) {
        int rr = wm + im * 16 + l16;
        av[im] = *reinterpret_cast<const short8*>(
            cA + rr * 64 + (((ks * 4 + quad) ^ (rr & 7)) * 8));
      }
#pragma unroll
      for (int in = 0; in < 4; ++in) {
        int rr = wn + in * 16 + l16;
        bv[in] = *reinterpret_cast<const short8*>(
            cB + rr * 64 + (((ks * 4 + quad) ^ (rr & 7)) * 8));
      }
#pragma unroll
      for (int im = 0; im < 4; ++im)
#pragma unroll
        for (int in = 0; in < 4; ++in)
          acc[im][in] = __builtin_amdgcn_mfma_f32_16x16x32_bf16(av[im], bv[in], acc[im][in], 0, 0, 0);
    }
    __syncthreads();
    cur ^= 1;
  }

  ushort_t* sC = sm;  // [128 o][136] bf16, transposed store
#pragma unroll
  for (int in = 0; in < 4; ++in) {
    int ol = wn + in * 16 + l16;
    float bv_ = bias[n0 + ol];
#pragma unroll
    for (int im = 0; im < 4; ++im)
#pragma unroll
      for (int r = 0; r < 4; ++r) {
        int mr = wm + im * 16 + quad * 4 + r;
        sC[ol * 136 + mr] = f2b(acc[im][in][r] + bv_);
      }
  }
  __syncthreads();
#pragma unroll
  for (int i = 0; i < 16; ++i) {
    int cid = i * 256 + tid;
    int o = cid >> 5, ch = cid & 31;
    uint2 pk = *reinterpret_cast<const uint2*>(sC + o * 136 + ch * 4);
    size_t gidx;
    if (isv) {
      int b = m0 >> 12, f = (m0 >> 8) & 15, hw0 = m0 & 255;
      gidx = ((size_t)((b * 16 + f) * 768 + n0 + o)) * 256 + hw0 + ch * 4;
    } else {
      int b = m0 >> 10, t0 = m0 & 1023;
      gidx = ((size_t)(b * 768 + n0 + o)) * 1024 + t0 + ch * 4;
    }
    float4 rv = *reinterpret_cast<const float4*>(resp + gidx);
    float4 ov;
    ov.x = rv.x + b2f(pk.x & 0xffff);
    ov.y = rv.y + b2f(pk.x >> 16);
    ov.z = rv.z + b2f(pk.y & 0xffff);
    ov.w = rv.w + b2f(pk.y >> 16);
    *reinterpret_cast<float4*>(outp + gidx) = ov;
  }
}

// ---------------------------------------------------------------------------
// Fused MFMA flash attention. Segment-local XCD swizzle, heavy audio-q blocks
// dispatched first:
//   bx0 0..767    -> audio-q segment (NT=8), swz within 768 = 8*96
//   bx0 768..3839 -> video-q segment (NT=2), swz within 3072 = 8*384
// Staged LDS path, exp2-domain softmax (Q pre-scaled by log2 e), ones-MFMA
// row-sum, round-half-up P->bf16, max3 chains.
// ---------------------------------------------------------------------------
__global__ __launch_bounds__(256) void attn_fused_kernel(
    const ushort_t* __restrict__ Qv, const ushort_t* __restrict__ Ka,
    const ushort_t* __restrict__ Va, ushort_t* __restrict__ Ov,
    const ushort_t* __restrict__ Qa, const ushort_t* __restrict__ Kv,
    const ushort_t* __restrict__ Vv, ushort_t* __restrict__ Oa) {
  __shared__ ushort_t sm[37376];       // 74752 B
  ushort_t* sQ = sm;                   // [64][64]  xor8
  ushort_t* sK = sm + 4096;            // [128][64] xor8
  ushort_t* sV0 = sm + 12288;          // [64][128] xor16
  ushort_t* sV1 = sm + 20480;
  ushort_t* sP = sm + 28672;           // [64][136] P bf16 / O bounce
  const int tid = threadIdx.x;
  const int lane = tid & 63, wave = tid >> 6;
  const int quad = lane >> 4, l16 = lane & 15;

  // Segment-local XCD swizzle; heavy audio-q segment dispatched first.
  const int bx0 = blockIdx.x;
  const bool isv = bx0 >= 768;
  int lb;
  if (isv) {
    int local = bx0 - 768;             // 3072 = 8 * 384
    lb = (local & 7) * 384 + (local >> 3);
  } else {
    int local = bx0;                   // 768 = 8 * 96
    lb = (local & 7) * 96 + (local >> 3);
  }

  const ushort_t* Qt = isv ? Qv : Qa;
  const ushort_t* Kt = isv ? Ka : Kv;
  const ushort_t* Vc = isv ? Va : Vv;
  ushort_t* Ot = isv ? Ov : Oa;
  const int qlog = isv ? 4 : 2;        // NQT = 16 / 4
  const int NT = isv ? 2 : 8;          // SW/128
  const int QW = isv ? 1024 : 256;
  const int SW = isv ? 256 : 1024;
  const int TQb = isv ? 4096 : 1024;
  const int TSb = isv ? 1024 : 4096;
  const int Ms = isv ? 4096 : 16384;

  const int qt = lb & ((1 << qlog) - 1);
  const int win = (lb >> qlog) & 3;
  const int whb = lb >> (qlog + 2);
  const int h = whb % 12;
  const int batch = whb / 12;
  const int hc = h * 64;
  const int nq0 = batch * TQb + win * QW + qt * 64;
  const int ns_base = batch * TSb + win * SW;

  const int r8 = lane >> 3, c8 = lane & 7;
  const int s8 = (c8 ^ r8) * 8;
  const int r16 = lane >> 4, c16 = lane & 15;

  auto stage_k = [&](int ns0) {
#pragma unroll
    for (int i = 0; i < 4; ++i) {
      int row = wave * 32 + i * 8 + r8;
      gl_lds16(Kt + (size_t)(ns0 + row) * 768 + hc + s8, sK + (wave * 32 + i * 8) * 64);
    }
  };
  auto stage_v = [&](int ns0, ushort_t* sV) {
#pragma unroll
    for (int i = 0; i < 4; ++i) {
      int ch = wave * 16 + i * 4 + r16;
      int slot = c16 ^ (i * 4 + r16);
      gl_lds16(Vc + (size_t)(hc + ch) * Ms + ns0 + slot * 8, sV + (wave * 16 + i * 4) * 128);
    }
  };

#pragma unroll
  for (int i = 0; i < 2; ++i) {
    int row = wave * 16 + i * 8 + r8;
    gl_lds16(Qt + (size_t)(nq0 + row) * 768 + hc + s8, sQ + (wave * 16 + i * 8) * 64);
  }
  stage_k(ns_base);
  stage_v(ns_base, sV0);
  __syncthreads();

  short8 qf[2];
#pragma unroll
  for (int ks = 0; ks < 2; ++ks)
    qf[ks] = *reinterpret_cast<const short8*>(
        sQ + (wave * 16 + l16) * 64 + (((ks * 4 + quad) ^ (l16 & 7)) * 8));

  const short8 vones = {0x3F80, 0x3F80, 0x3F80, 0x3F80, 0x3F80, 0x3F80, 0x3F80, 0x3F80};

  float mr[4];
  f32x4 on[4], onl;
#pragma unroll
  for (int r = 0; r < 4; ++r) mr[r] = -1e30f;
#pragma unroll
  for (int nc = 0; nc < 4; ++nc) on[nc] = (f32x4){0.f, 0.f, 0.f, 0.f};
  onl = (f32x4){0.f, 0.f, 0.f, 0.f};
  const int prow0 = (wave * 16 + quad * 4) * 136;

  for (int t = 0; t < NT; ++t) {
    if (t + 1 < NT) stage_v(ns_base + (t + 1) * 128, (t & 1) ? sV0 : sV1);
    f32x4 sf[8];
#pragma unroll
    for (int nt = 0; nt < 8; ++nt) sf[nt] = (f32x4){0.f, 0.f, 0.f, 0.f};
#pragma unroll
    for (int ks = 0; ks < 2; ++ks) {
#pragma unroll
      for (int nt = 0; nt < 8; ++nt) {
        short8 kf = *reinterpret_cast<const short8*>(
            sK + (nt * 16 + l16) * 64 + (((ks * 4 + quad) ^ (l16 & 7)) * 8));
        sf[nt] = __builtin_amdgcn_mfma_f32_16x16x32_bf16(qf[ks], kf, sf[nt], 0, 0, 0);
      }
    }
    __syncthreads();
    if (t + 1 < NT) stage_k(ns_base + (t + 1) * 128);
    // ---- online softmax in exp2 domain; row-sum deferred to ones-MFMA
#pragma unroll
    for (int r = 0; r < 4; ++r) {
      float m_ = fmaxf(fmaxf(sf[0][r], sf[1][r]), sf[2][r]);
      m_ = fmaxf(fmaxf(m_, sf[3][r]), sf[4][r]);
      m_ = fmaxf(fmaxf(m_, sf[5][r]), sf[6][r]);
      m_ = fmaxf(m_, sf[7][r]);
#pragma unroll
      for (int off = 1; off < 16; off <<= 1) m_ = fmaxf(m_, __shfl_xor(m_, off));
      float mnew = fmaxf(mr[r], m_);
      float al = __builtin_amdgcn_exp2f(mr[r] - mnew);
      mr[r] = mnew;
      int prow = prow0 + r * 136;
#pragma unroll
      for (int nt = 0; nt < 8; ++nt) {
        float p = __builtin_amdgcn_exp2f(sf[nt][r] - mnew);
        sP[prow + nt * 16 + l16] = (ushort_t)((__float_as_uint(p) + 0x8000u) >> 16);
      }
#pragma unroll
      for (int nc = 0; nc < 4; ++nc) on[nc][r] *= al;
      onl[r] *= al;
    }
    // ---- O += P V ; l += P 1 (ones-MFMA row-sum)
    const ushort_t* sV = (t & 1) ? sV1 : sV0;
#pragma unroll
    for (int ks = 0; ks < 4; ++ks) {
      short8 pf = *reinterpret_cast<const short8*>(sP + (wave * 16 + l16) * 136 + ks * 32 + quad * 8);
#pragma unroll
      for (int nc = 0; nc < 4; ++nc) {
        short8 vf = *reinterpret_cast<const short8*>(
            sV + (nc * 16 + l16) * 128 + (((ks * 4 + quad) ^ l16) * 8));
        on[nc] = __builtin_amdgcn_mfma_f32_16x16x32_bf16(pf, vf, on[nc], 0, 0, 0);
      }
      onl = __builtin_amdgcn_mfma_f32_16x16x32_bf16(pf, vones, onl, 0, 0, 0);
    }
    if (t + 1 < NT) __syncthreads();
  }
#pragma unroll
  for (int r = 0; r < 4; ++r) {
    float inv = 1.f / onl[r];
    int prow = prow0 + r * 136;
#pragma unroll
    for (int nc = 0; nc < 4; ++nc)
      sP[prow + nc * 16 + l16] = f2b(on[nc][r] * inv);
  }
  __syncthreads();
#pragma unroll
  for (int i = 0; i < 2; ++i) {
    int c = i * 256 + tid;
    int row = c >> 3, cc = c & 7;
    *reinterpret_cast<uint4*>(Ot + (size_t)(nq0 + row) * 768 + hc + cc * 8) =
        *reinterpret_cast<const uint4*>(sP + row * 136 + cc * 8);
  }
}

// ---------------------------------------------------------------------------
extern "C" void kernel_launch(void* const* d_in, const int* in_sizes, int n_in,
                              void* d_out, int out_size, void* d_ws, size_t ws_size,
                              hipStream_t stream) {
  (void)in_sizes; (void)n_in; (void)out_size; (void)ws_size;
  const float* video = (const float*)d_in[0];
  const float* audio = (const float*)d_in[1];
  const float* vn_s = (const float*)d_in[2];
  const float* vn_b = (const float*)d_in[3];
  const float* an_s = (const float*)d_in[4];
  const float* an_b = (const float*)d_in[5];
  const float* vqkv_w = (const float*)d_in[6];
  const float* vqkv_b = (const float*)d_in[7];
  const float* aqkv_w = (const float*)d_in[8];
  const float* aqkv_b = (const float*)d_in[9];
  const float* vproj_w = (const float*)d_in[10];
  const float* vproj_b = (const float*)d_in[11];
  const float* aproj_w = (const float*)d_in[12];
  const float* aproj_b = (const float*)d_in[13];

  float* out_v = (float*)d_out;
  float* out_a = out_v + (size_t)4 * 16 * 768 * 16 * 16;

  char* ws = (char*)d_ws;
  size_t off = 0;
  auto carve = [&](size_t bytes) {
    char* p = ws + off;
    off += (bytes + 255) & ~(size_t)255;
    return p;
  };
  float* part = (float*)carve(2560 * 2 * 4);
  ushort_t* Xv = (ushort_t*)carve((size_t)16384 * 768 * 2);
  ushort_t* Xa = (ushort_t*)carve((size_t)4096 * 768 * 2);
  ushort_t* Wqv = (ushort_t*)carve((size_t)2304 * 768 * 2);
  ushort_t* Wqa = (ushort_t*)carve((size_t)2304 * 768 * 2);
  ushort_t* Wpv = (ushort_t*)carve((size_t)768 * 768 * 2);
  ushort_t* Wpa = (ushort_t*)carve((size_t)768 * 768 * 2);
  ushort_t* Qv = (ushort_t*)carve((size_t)16384 * 768 * 2);
  ushort_t* Kv = (ushort_t*)carve((size_t)16384 * 768 * 2);
  ushort_t* Vv = (ushort_t*)carve((size_t)16384 * 768 * 2);
  ushort_t* Qa = (ushort_t*)carve((size_t)4096 * 768 * 2);
  ushort_t* Ka = (ushort_t*)carve((size_t)4096 * 768 * 2);
  ushort_t* Va = (ushort_t*)carve((size_t)4096 * 768 * 2);
  ushort_t* Ov = Xv;  // alias: X no longer needed after QKV GEMM
  ushort_t* Oa = Xa;

  fused_pre_kernel<<<3584, 256, 0, stream>>>(video, audio, part,
                                             vqkv_w, aqkv_w, vproj_w, aproj_w,
                                             Wqv, Wqa, Wpv, Wpa);
  norm_fused_kernel<<<1920, 256, 0, stream>>>(video, audio, part,
                                              vn_s, vn_b, an_s, an_b, Xv, Xa);
  qkv_fused_kernel<<<2880, 256, 0, stream>>>(Xv, Xa, Wqv, Wqa, vqkv_b, aqkv_b,
                                             Qv, Kv, Vv, Qa, Ka, Va);
  attn_fused_kernel<<<3840, 256, 0, stream>>>(Qv, Ka, Va, Ov, Qa, Kv, Vv, Oa);
  proj_fused_kernel<<<960, 256, 0, stream>>>(Ov, Oa, Wpv, Wpa, vproj_b, aproj_b,
                                             out_v, video, out_a, audio);
}

// Round 10
// 324.915 us; speedup vs baseline: 2.1707x; 1.0307x over previous
//
#include <hip/hip_runtime.h>
#include <hip/hip_bf16.h>

typedef unsigned short ushort_t;
typedef __attribute__((ext_vector_type(8))) short short8;
typedef __attribute__((ext_vector_type(4))) float f32x4;
struct __align__(8) us4 { ushort_t x, y, z, w; };

#define DI __device__ __forceinline__

DI float b2f(unsigned int u16) {
  union { unsigned int i; float f; } v;
  v.i = u16 << 16;
  return v.f;
}
DI ushort_t f2b(float f) {
  union { float f; unsigned int u; } v; v.f = f;
  unsigned int r = v.u + 0x7FFFu + ((v.u >> 16) & 1u);
  return (ushort_t)(r >> 16);
}

// async global->LDS 16B copy: LDS dest is wave-uniform base + lane*16
DI void gl_lds16(const ushort_t* g, ushort_t* l) {
  __builtin_amdgcn_global_load_lds(
      (const __attribute__((address_space(1))) unsigned int*)g,
      (__attribute__((address_space(3))) unsigned int*)l, 16, 0, 0);
}

// ---------------------------------------------------------------------------
// Fused: GroupNorm partial stats (blocks 0..2559) + weight bf16 cvt (2560..3583)
// All loads float4 (16B/lane); wcvt emits ushort4 (8B/lane).
// ---------------------------------------------------------------------------
__global__ __launch_bounds__(256) void fused_pre_kernel(
    const float* __restrict__ video, const float* __restrict__ audio,
    float* __restrict__ part,
    const float* __restrict__ w0, const float* __restrict__ w1,
    const float* __restrict__ w2, const float* __restrict__ w3,
    ushort_t* __restrict__ o0, ushort_t* __restrict__ o1,
    ushort_t* __restrict__ o2, ushort_t* __restrict__ o3) {
  const int bid = blockIdx.x;
  const int tid = threadIdx.x;
  __shared__ float red[8];
  if (bid < 2560) {
    float s = 0.f, ss = 0.f;
    if (bid < 2048) {
      int bg = bid >> 4, f = bid & 15;
      int b = bg >> 5, g = bg & 31;
      // 24ch x 256hw slab is 6144 contiguous floats = 1536 float4
      const float4* base = reinterpret_cast<const float4*>(
          video + ((size_t)((b * 16 + f) * 768 + g * 24)) * 256);
#pragma unroll
      for (int i = 0; i < 6; ++i) {
        float4 v = base[i * 256 + tid];
        s += v.x + v.y + v.z + v.w;
        ss += v.x * v.x + v.y * v.y + v.z * v.z + v.w * v.w;
      }
    } else {
      int a = bid - 2048;
      int bg = a >> 2, p = a & 3;
      int b = bg >> 5, g = bg & 31;
      // 24 rows (stride 1024), 256 floats each: 4 rows/pass x 64 float4
      const float* ab = audio + ((size_t)(b * 768 + g * 24)) * 1024 + p * 256;
#pragma unroll
      for (int i = 0; i < 6; ++i) {
        int row = i * 4 + (tid >> 6);
        float4 v = *reinterpret_cast<const float4*>(ab + (size_t)row * 1024 + (tid & 63) * 4);
        s += v.x + v.y + v.z + v.w;
        ss += v.x * v.x + v.y * v.y + v.z * v.z + v.w * v.w;
      }
    }
    for (int off = 32; off > 0; off >>= 1) { s += __shfl_down(s, off, 64); ss += __shfl_down(ss, off, 64); }
    int wv = tid >> 6, ln = tid & 63;
    if (ln == 0) { red[wv * 2] = s; red[wv * 2 + 1] = ss; }
    __syncthreads();
    if (tid == 0) {
      part[bid * 2] = red[0] + red[2] + red[4] + red[6];
      part[bid * 2 + 1] = red[1] + red[3] + red[5] + red[7];
    }
  } else {
    // weight cvt in float4 -> ushort4 units
    const int n1 = (2304 * 768) / 4, n3 = (768 * 768) / 4;
    const int total = 2 * n1 + 2 * n3;
    int wb = bid - 2560;
    for (int i = wb * 256 + tid; i < total; i += 1024 * 256) {
      const float4* src;
      ushort_t* dst;
      int j;
      if (i < n1) { src = (const float4*)w0; dst = o0; j = i; }
      else if (i < 2 * n1) { src = (const float4*)w1; dst = o1; j = i - n1; }
      else if (i < 2 * n1 + n3) { src = (const float4*)w2; dst = o2; j = i - 2 * n1; }
      else { src = (const float4*)w3; dst = o3; j = i - 2 * n1 - n3; }
      float4 v = src[j];
      us4 o = {f2b(v.x), f2b(v.y), f2b(v.z), f2b(v.w)};
      *reinterpret_cast<us4*>(dst + (size_t)j * 4) = o;
    }
  }
}

// ---------------------------------------------------------------------------
// Fused normalize (gn_final folded in: per-block channel stats from `part`).
// Blocks 0..1535: video -> Xv[n][c]; 1536..1919: audio -> Xa[n][c].
// float4 loads (one wave = one full 1KB row), ushort4 stores (4 ch/lane).
// ---------------------------------------------------------------------------
__global__ __launch_bounds__(256) void norm_fused_kernel(
    const float* __restrict__ video, const float* __restrict__ audio,
    const float* __restrict__ part,
    const float* __restrict__ vsc, const float* __restrict__ vbi,
    const float* __restrict__ asc, const float* __restrict__ abi,
    ushort_t* __restrict__ Xv, ushort_t* __restrict__ Xa) {
  __shared__ float T[32][257];
  __shared__ float shA[32], shB[32];  // per-channel scale/shift: y = A*x + B
  const int bx = blockIdx.x;
  const int tid = threadIdx.x;
  if (bx < 1536) {
    const int bf = bx / 24, ct = bx % 24;
    const int b = bf >> 4, f = bf & 15;
    const int c0 = ct * 32;
    if (tid < 32) {
      int c = c0 + tid, g = c / 24;
      float s = 0.f, ss = 0.f;
#pragma unroll
      for (int i = 0; i < 16; ++i) {
        s += part[((b * 32 + g) * 16 + i) * 2];
        ss += part[((b * 32 + g) * 16 + i) * 2 + 1];
      }
      const float N = 24.f * 4096.f;
      float m = s / N;
      float r = rsqrtf(ss / N - m * m + 1e-5f);
      float A = r * vsc[c];
      shA[tid] = A;
      shB[tid] = vbi[c] - m * A;
    }
    __syncthreads();
    // load+normalize: 32 rows x 64 float4; one wave covers one row per iter
#pragma unroll
    for (int i = 0; i < 8; ++i) {
      int idx = i * 256 + tid;
      int c = idx >> 6, q4 = idx & 63;
      float4 v = *reinterpret_cast<const float4*>(
          video + ((size_t)((b * 16 + f) * 768 + c0 + c)) * 256 + q4 * 4);
      float A = shA[c], B = shB[c];
      float4 o = {A * v.x + B, A * v.y + B, A * v.z + B, A * v.w + B};
      *reinterpret_cast<float4*>(&T[c][q4 * 4]) = o;
    }
    __syncthreads();
    // store token-major: 256 hw x 8 ch-quads; ushort4 per lane
#pragma unroll
    for (int i = 0; i < 8; ++i) {
      int idx = i * 256 + tid;
      int c4 = idx & 7, hw = idx >> 3;
      us4 o = {f2b(T[c4 * 4 + 0][hw]), f2b(T[c4 * 4 + 1][hw]),
               f2b(T[c4 * 4 + 2][hw]), f2b(T[c4 * 4 + 3][hw])};
      *reinterpret_cast<us4*>(Xv + ((size_t)(b * 4096 + f * 256 + hw)) * 768 + c0 + c4 * 4) = o;
    }
  } else {
    const int ax = bx - 1536;
    const int bt = ax / 24, ct = ax % 24;
    const int b = bt >> 2, t0 = (bt & 3) * 256;
    const int c0 = ct * 32;
    if (tid < 32) {
      int c = c0 + tid, g = c / 24;
      float s = 0.f, ss = 0.f;
#pragma unroll
      for (int i = 0; i < 4; ++i) {
        s += part[(2048 + (b * 32 + g) * 4 + i) * 2];
        ss += part[(2048 + (b * 32 + g) * 4 + i) * 2 + 1];
      }
      const float N = 24.f * 1024.f;
      float m = s / N;
      float r = rsqrtf(ss / N - m * m + 1e-5f);
      float A = r * asc[c];
      shA[tid] = A;
      shB[tid] = abi[c] - m * A;
    }
    __syncthreads();
#pragma unroll
    for (int i = 0; i < 8; ++i) {
      int idx = i * 256 + tid;
      int c = idx >> 6, q4 = idx & 63;
      float4 v = *reinterpret_cast<const float4*>(
          audio + ((size_t)(b * 768 + c0 + c)) * 1024 + t0 + q4 * 4);
      float A = shA[c], B = shB[c];
      float4 o = {A * v.x + B, A * v.y + B, A * v.z + B, A * v.w + B};
      *reinterpret_cast<float4*>(&T[c][q4 * 4]) = o;
    }
    __syncthreads();
#pragma unroll
    for (int i = 0; i < 8; ++i) {
      int idx = i * 256 + tid;
      int c4 = idx & 7, tt = idx >> 3;
      us4 o = {f2b(T[c4 * 4 + 0][tt]), f2b(T[c4 * 4 + 1][tt]),
               f2b(T[c4 * 4 + 2][tt]), f2b(T[c4 * 4 + 3][tt])};
      *reinterpret_cast<us4*>(Xa + ((size_t)(b * 1024 + t0 + tt)) * 768 + c0 + c4 * 4) = o;
    }
  }
}

// ---------------------------------------------------------------------------
// Fused QKV GEMM (video blocks 0..2303, audio 2304..2879).
// 128x128 tile, 2-phase dbuf gl_lds16 staging, XOR chunk swizzle both sides,
// segment-local XCD bijective block swizzle.
// Q section pre-scaled by 0.125*log2(e): attention softmax runs in exp2 domain.
// ---------------------------------------------------------------------------
__global__ __launch_bounds__(256) void qkv_fused_kernel(
    const ushort_t* __restrict__ Xv, const ushort_t* __restrict__ Xa,
    const ushort_t* __restrict__ Wqv, const ushort_t* __restrict__ Wqa,
    const float* __restrict__ vqkv_b, const float* __restrict__ aqkv_b,
    ushort_t* __restrict__ Qv, ushort_t* __restrict__ Kv, ushort_t* __restrict__ Vv,
    ushort_t* __restrict__ Qa, ushort_t* __restrict__ Ka, ushort_t* __restrict__ Va) {
  __shared__ ushort_t sm[32768];  // 64 KiB dbuf
  const int bid = blockIdx.x;
  const int tid = threadIdx.x;
  const int lane = tid & 63, wave = tid >> 6;
  const int quad = lane >> 4, l16 = lane & 15;

  const bool isv = bid < 2304;
  const int lb = isv ? bid : bid - 2304;
  const int nwg = isv ? 2304 : 576;
  const ushort_t* A = isv ? Xv : Xa;
  const ushort_t* W = isv ? Wqv : Wqa;
  const float* bias = isv ? vqkv_b : aqkv_b;
  ushort_t* pQ = isv ? Qv : Qa;
  ushort_t* pK = isv ? Kv : Ka;
  ushort_t* pV = isv ? Vv : Va;
  const int M = isv ? 16384 : 4096;

  const int lid = (lb & 7) * (nwg >> 3) + (lb >> 3);
  const int n0 = (lid % 18) * 128, m0 = (lid / 18) * 128;
  const int wm = (wave & 1) * 64, wn = (wave >> 1) * 64;

  const int srow = wave * 32 + (lane >> 3);
  const int sq = ((lane & 7) ^ (lane >> 3)) * 8;
  const ushort_t* gA = A + (size_t)(m0 + srow) * 768 + sq;
  const ushort_t* gB = W + (size_t)(n0 + srow) * 768 + sq;

  f32x4 acc[4][4];
#pragma unroll
  for (int i = 0; i < 4; ++i)
#pragma unroll
    for (int j = 0; j < 4; ++j) acc[i][j] = (f32x4){0.f, 0.f, 0.f, 0.f};

  auto stage = [&](int kc, int cur) {
    ushort_t* lA = sm + cur * 8192 + wave * 2048;
    ushort_t* lB = sm + 16384 + cur * 8192 + wave * 2048;
#pragma unroll
    for (int i = 0; i < 4; ++i) {
      gl_lds16(gA + (size_t)i * 8 * 768 + kc, lA + i * 512);
      gl_lds16(gB + (size_t)i * 8 * 768 + kc, lB + i * 512);
    }
  };

  stage(0, 0);
  __syncthreads();
  int cur = 0;
  for (int t = 0; t < 12; ++t) {
    if (t < 11) stage((t + 1) * 64, cur ^ 1);
    const ushort_t* cA = sm + cur * 8192;
    const ushort_t* cB = sm + 16384 + cur * 8192;
#pragma unroll
    for (int ks = 0; ks < 2; ++ks) {
      short8 av[4], bv[4];
#pragma unroll
      for (int im = 0; im < 4; ++im) {
        int rr = wm + im * 16 + l16;
        av[im] = *reinterpret_cast<const short8*>(
            cA + rr * 64 + (((ks * 4 + quad) ^ (rr & 7)) * 8));
      }
#pragma unroll
      for (int in = 0; in < 4; ++in) {
        int rr = wn + in * 16 + l16;
        bv[in] = *reinterpret_cast<const short8*>(
            cB + rr * 64 + (((ks * 4 + quad) ^ (rr & 7)) * 8));
      }
#pragma unroll
      for (int im = 0; im < 4; ++im)
#pragma unroll
        for (int in = 0; in < 4; ++in)
          acc[im][in] = __builtin_amdgcn_mfma_f32_16x16x32_bf16(av[im], bv[in], acc[im][in], 0, 0, 0);
    }
    __syncthreads();
    cur ^= 1;
  }

  ushort_t* sC = sm;  // epilogue scratch [128][136] bf16
  const int section = n0 / 768;  // 0=Q 1=K 2=V
  const int obase = n0 - section * 768;
  if (section < 2) {
    // fold qk scale AND log2(e) into Q: softmax uses native exp2
    const float qs = (section == 0) ? 0.125f * 1.44269504088896340736f : 1.0f;
#pragma unroll
    for (int in = 0; in < 4; ++in) {
      int ol = wn + in * 16 + l16;
      float bv_ = bias[n0 + ol];
#pragma unroll
      for (int im = 0; im < 4; ++im)
#pragma unroll
        for (int r = 0; r < 4; ++r) {
          int row = wm + im * 16 + quad * 4 + r;
          sC[row * 136 + ol] = f2b((acc[im][in][r] + bv_) * qs);
        }
    }
    __syncthreads();
    ushort_t* dst = (section == 0) ? pQ : pK;
#pragma unroll
    for (int i = 0; i < 8; ++i) {
      int cid = i * 256 + tid;
      int row = cid >> 4, ch = cid & 15;
      *reinterpret_cast<uint4*>(dst + (size_t)(m0 + row) * 768 + obase + ch * 8) =
          *reinterpret_cast<const uint4*>(sC + row * 136 + ch * 8);
    }
  } else {
#pragma unroll
    for (int in = 0; in < 4; ++in) {
      int ol = wn + in * 16 + l16;
      float bv_ = bias[n0 + ol];
#pragma unroll
      for (int im = 0; im < 4; ++im)
#pragma unroll
        for (int r = 0; r < 4; ++r) {
          int mr = wm + im * 16 + quad * 4 + r;
          sC[ol * 136 + mr] = f2b(acc[im][in][r] + bv_);
        }
    }
    __syncthreads();
#pragma unroll
    for (int i = 0; i < 8; ++i) {
      int cid = i * 256 + tid;
      int o = cid >> 4, ch = cid & 15;
      *reinterpret_cast<uint4*>(pV + (size_t)(obase + o) * M + m0 + ch * 8) =
          *reinterpret_cast<const uint4*>(sC + o * 136 + ch * 8);
    }
  }
}

// ---------------------------------------------------------------------------
// Fused proj GEMM + residual (video blocks 0..767, audio 768..959)
// ---------------------------------------------------------------------------
__global__ __launch_bounds__(256) void proj_fused_kernel(
    const ushort_t* __restrict__ Ov, const ushort_t* __restrict__ Oa,
    const ushort_t* __restrict__ Wpv, const ushort_t* __restrict__ Wpa,
    const float* __restrict__ vproj_b, const float* __restrict__ aproj_b,
    float* __restrict__ out_v, const float* __restrict__ video,
    float* __restrict__ out_a, const float* __restrict__ audio) {
  __shared__ ushort_t sm[32768];
  const int bid = blockIdx.x;
  const int tid = threadIdx.x;
  const int lane = tid & 63, wave = tid >> 6;
  const int quad = lane >> 4, l16 = lane & 15;

  const bool isv = bid < 768;
  const int lb = isv ? bid : bid - 768;
  const int nwg = isv ? 768 : 192;
  const ushort_t* A = isv ? Ov : Oa;
  const ushort_t* W = isv ? Wpv : Wpa;
  const float* bias = isv ? vproj_b : aproj_b;
  float* outp = isv ? out_v : out_a;
  const float* resp = isv ? video : audio;

  const int lid = (lb & 7) * (nwg >> 3) + (lb >> 3);
  const int n0 = (lid % 6) * 128, m0 = (lid / 6) * 128;
  const int wm = (wave & 1) * 64, wn = (wave >> 1) * 64;

  const int srow = wave * 32 + (lane >> 3);
  const int sq = ((lane & 7) ^ (lane >> 3)) * 8;
  const ushort_t* gA = A + (size_t)(m0 + srow) * 768 + sq;
  const ushort_t* gB = W + (size_t)(n0 + srow) * 768 + sq;

  f32x4 acc[4][4];
#pragma unroll
  for (int i = 0; i < 4; ++i)
#pragma unroll
    for (int j = 0; j < 4; ++j) acc[i][j] = (f32x4){0.f, 0.f, 0.f, 0.f};

  auto stage = [&](int kc, int cur) {
    ushort_t* lA = sm + cur * 8192 + wave * 2048;
    ushort_t* lB = sm + 16384 + cur * 8192 + wave * 2048;
#pragma unroll
    for (int i = 0; i < 4; ++i) {
      gl_lds16(gA + (size_t)i * 8 * 768 + kc, lA + i * 512);
      gl_lds16(gB + (size_t)i * 8 * 768 + kc, lB + i * 512);
    }
  };

  stage(0, 0);
  __syncthreads();
  int cur = 0;
  for (int t = 0; t < 12; ++t) {
    if (t < 11) stage((t + 1) * 64, cur ^ 1);
    const ushort_t* cA = sm + cur * 8192;
    const ushort_t* cB = sm + 16384 + cur * 8192;
#pragma unroll
    for (int ks = 0; ks < 2; ++ks) {
      short8 av[4], bv[4];
#pragma unroll
      for (int im = 0; im < 4; ++im) {
        int rr = wm + im * 16 + l16;
        av[im] = *reinterpret_cast<const short8*>(
            cA + rr * 64 + (((ks * 4 + quad) ^ (rr & 7)) * 8));
      }
#pragma unroll
      for (int in = 0; in < 4; ++in) {
        int rr = wn + in * 16 + l16;
        bv[in] = *reinterpret_cast<const short8*>(
            cB + rr * 64 + (((ks * 4 + quad) ^ (rr & 7)) * 8));
      }
#pragma unroll
      for (int im = 0; im < 4; ++im)
#pragma unroll
        for (int in = 0; in < 4; ++in)
          acc[im][in] = __builtin_amdgcn_mfma_f32_16x16x32_bf16(av[im], bv[in], acc[im][in], 0, 0, 0);
    }
    __syncthreads();
    cur ^= 1;
  }

  ushort_t* sC = sm;  // [128 o][136] bf16, transposed store
#pragma unroll
  for (int in = 0; in < 4; ++in) {
    int ol = wn + in * 16 + l16;
    float bv_ = bias[n0 + ol];
#pragma unroll
    for (int im = 0; im < 4; ++im)
#pragma unroll
      for (int r = 0; r < 4; ++r) {
        int mr = wm + im * 16 + quad * 4 + r;
        sC[ol * 136 + mr] = f2b(acc[im][in][r] + bv_);
      }
  }
  __syncthreads();
#pragma unroll
  for (int i = 0; i < 16; ++i) {
    int cid = i * 256 + tid;
    int o = cid >> 5, ch = cid & 31;
    uint2 pk = *reinterpret_cast<const uint2*>(sC + o * 136 + ch * 4);
    size_t gidx;
    if (isv) {
      int b = m0 >> 12, f = (m0 >> 8) & 15, hw0 = m0 & 255;
      gidx = ((size_t)((b * 16 + f) * 768 + n0 + o)) * 256 + hw0 + ch * 4;
    } else {
      int b = m0 >> 10, t0 = m0 & 1023;
      gidx = ((size_t)(b * 768 + n0 + o)) * 1024 + t0 + ch * 4;
    }
    float4 rv = *reinterpret_cast<const float4*>(resp + gidx);
    float4 ov;
    ov.x = rv.x + b2f(pk.x & 0xffff);
    ov.y = rv.y + b2f(pk.x >> 16);
    ov.z = rv.z + b2f(pk.y & 0xffff);
    ov.w = rv.w + b2f(pk.y >> 16);
    *reinterpret_cast<float4*>(outp + gidx) = ov;
  }
}

// ---------------------------------------------------------------------------
// Fused MFMA flash attention. Segment-local XCD swizzle, heavy audio-q blocks
// dispatched first. Round-10 change: LDS diet 74.75KB -> 50.2KB for 3
// blocks/CU (was 2): sQ aliases sP (Q in regs before first sP write) and the
// V double-buffer is dropped -- stage_v(t+1) issues after the post-PV barrier
// and its latency hides under QK(t+1) + the extra resident blocks.
// Schedule (2 barriers/tile, drains via __syncthreads' implicit vmcnt(0)):
//   loop t: QK(t)[sK] ; B1 (drains V(t)) ; stage_k(t+1) ; softmax -> sP ;
//           PV(t)[sV,sP] ; if t+1<NT { B2 (drains K(t+1)) ; stage_v(t+1) }
// Keeps: exp2-domain softmax, ones-MFMA row-sum, cheap P->bf16, max3 chains.
// ---------------------------------------------------------------------------
__global__ __launch_bounds__(256) void attn_fused_kernel(
    const ushort_t* __restrict__ Qv, const ushort_t* __restrict__ Ka,
    const ushort_t* __restrict__ Va, ushort_t* __restrict__ Ov,
    const ushort_t* __restrict__ Qa, const ushort_t* __restrict__ Kv,
    const ushort_t* __restrict__ Vv, ushort_t* __restrict__ Oa) {
  __shared__ ushort_t sm[25088];       // 50176 B -> 3 blocks/CU
  ushort_t* sK = sm;                   // [128][64] xor8, 16 KB
  ushort_t* sV = sm + 8192;            // [64][128] xor16, 16 KB (single buffer)
  ushort_t* sP = sm + 16384;           // [64][136] P bf16 / O bounce, 17408 B
  ushort_t* sQ = sP;                   // alias: Q staged here, consumed to regs
                                       // before the first sP write (barrier-ordered)
  const int tid = threadIdx.x;
  const int lane = tid & 63, wave = tid >> 6;
  const int quad = lane >> 4, l16 = lane & 15;

  // Segment-local XCD swizzle; heavy audio-q segment dispatched first.
  const int bx0 = blockIdx.x;
  const bool isv = bx0 >= 768;
  int lb;
  if (isv) {
    int local = bx0 - 768;             // 3072 = 8 * 384
    lb = (local & 7) * 384 + (local >> 3);
  } else {
    int local = bx0;                   // 768 = 8 * 96
    lb = (local & 7) * 96 + (local >> 3);
  }

  const ushort_t* Qt = isv ? Qv : Qa;
  const ushort_t* Kt = isv ? Ka : Kv;
  const ushort_t* Vc = isv ? Va : Vv;
  ushort_t* Ot = isv ? Ov : Oa;
  const int qlog = isv ? 4 : 2;        // NQT = 16 / 4
  const int NT = isv ? 2 : 8;          // SW/128
  const int QW = isv ? 1024 : 256;
  const int SW = isv ? 256 : 1024;
  const int TQb = isv ? 4096 : 1024;
  const int TSb = isv ? 1024 : 4096;
  const int Ms = isv ? 4096 : 16384;

  const int qt = lb & ((1 << qlog) - 1);
  const int win = (lb >> qlog) & 3;
  const int whb = lb >> (qlog + 2);
  const int h = whb % 12;
  const int batch = whb / 12;
  const int hc = h * 64;
  const int nq0 = batch * TQb + win * QW + qt * 64;
  const int ns_base = batch * TSb + win * SW;

  const int r8 = lane >> 3, c8 = lane & 7;
  const int s8 = (c8 ^ r8) * 8;
  const int r16 = lane >> 4, c16 = lane & 15;

  auto stage_k = [&](int ns0) {
#pragma unroll
    for (int i = 0; i < 4; ++i) {
      int row = wave * 32 + i * 8 + r8;
      gl_lds16(Kt + (size_t)(ns0 + row) * 768 + hc + s8, sK + (wave * 32 + i * 8) * 64);
    }
  };
  auto stage_v = [&](int ns0) {
#pragma unroll
    for (int i = 0; i < 4; ++i) {
      int ch = wave * 16 + i * 4 + r16;
      int slot = c16 ^ (i * 4 + r16);
      gl_lds16(Vc + (size_t)(hc + ch) * Ms + ns0 + slot * 8, sV + (wave * 16 + i * 4) * 128);
    }
  };

  // prologue: Q -> sQ (=sP alias), K(0), V(0); single drain
#pragma unroll
  for (int i = 0; i < 2; ++i) {
    int row = wave * 16 + i * 8 + r8;
    gl_lds16(Qt + (size_t)(nq0 + row) * 768 + hc + s8, sQ + (wave * 16 + i * 8) * 64);
  }
  stage_k(ns_base);
  stage_v(ns_base);
  __syncthreads();

  short8 qf[2];
#pragma unroll
  for (int ks = 0; ks < 2; ++ks)
    qf[ks] = *reinterpret_cast<const short8*>(
        sQ + (wave * 16 + l16) * 64 + (((ks * 4 + quad) ^ (l16 & 7)) * 8));

  const short8 vones = {0x3F80, 0x3F80, 0x3F80, 0x3F80, 0x3F80, 0x3F80, 0x3F80, 0x3F80};

  float mr[4];
  f32x4 on[4], onl;
#pragma unroll
  for (int r = 0; r < 4; ++r) mr[r] = -1e30f;
#pragma unroll
  for (int nc = 0; nc < 4; ++nc) on[nc] = (f32x4){0.f, 0.f, 0.f, 0.f};
  onl = (f32x4){0.f, 0.f, 0.f, 0.f};
  const int prow0 = (wave * 16 + quad * 4) * 136;

  for (int t = 0; t < NT; ++t) {
    // ---- S = Q K^T (sK holds tile t; V(t) loads may still be in flight)
    f32x4 sf[8];
#pragma unroll
    for (int nt = 0; nt < 8; ++nt) sf[nt] = (f32x4){0.f, 0.f, 0.f, 0.f};
#pragma unroll
    for (int ks = 0; ks < 2; ++ks) {
#pragma unroll
      for (int nt = 0; nt < 8; ++nt) {
        short8 kf = *reinterpret_cast<const short8*>(
            sK + (nt * 16 + l16) * 64 + (((ks * 4 + quad) ^ (l16 & 7)) * 8));
        sf[nt] = __builtin_amdgcn_mfma_f32_16x16x32_bf16(qf[ks], kf, sf[nt], 0, 0, 0);
      }
    }
    __syncthreads();  // B1: all waves done with sK; drains V(t) loads
    if (t + 1 < NT) stage_k(ns_base + (t + 1) * 128);  // overlaps softmax+PV
    // ---- online softmax in exp2 domain; row-sum deferred to ones-MFMA
#pragma unroll
    for (int r = 0; r < 4; ++r) {
      float m_ = fmaxf(fmaxf(sf[0][r], sf[1][r]), sf[2][r]);
      m_ = fmaxf(fmaxf(m_, sf[3][r]), sf[4][r]);
      m_ = fmaxf(fmaxf(m_, sf[5][r]), sf[6][r]);
      m_ = fmaxf(m_, sf[7][r]);
#pragma unroll
      for (int off = 1; off < 16; off <<= 1) m_ = fmaxf(m_, __shfl_xor(m_, off));
      float mnew = fmaxf(mr[r], m_);
      float al = __builtin_amdgcn_exp2f(mr[r] - mnew);
      mr[r] = mnew;
      int prow = prow0 + r * 136;
#pragma unroll
      for (int nt = 0; nt < 8; ++nt) {
        float p = __builtin_amdgcn_exp2f(sf[nt][r] - mnew);
        sP[prow + nt * 16 + l16] = (ushort_t)((__float_as_uint(p) + 0x8000u) >> 16);
      }
#pragma unroll
      for (int nc = 0; nc < 4; ++nc) on[nc][r] *= al;
      onl[r] *= al;
    }
    // ---- O += P V ; l += P 1 (ones-MFMA row-sum)
#pragma unroll
    for (int ks = 0; ks < 4; ++ks) {
      short8 pf = *reinterpret_cast<const short8*>(sP + (wave * 16 + l16) * 136 + ks * 32 + quad * 8);
#pragma unroll
      for (int nc = 0; nc < 4; ++nc) {
        short8 vf = *reinterpret_cast<const short8*>(
            sV + (nc * 16 + l16) * 128 + (((ks * 4 + quad) ^ l16) * 8));
        on[nc] = __builtin_amdgcn_mfma_f32_16x16x32_bf16(pf, vf, on[nc], 0, 0, 0);
      }
      onl = __builtin_amdgcn_mfma_f32_16x16x32_bf16(pf, vones, onl, 0, 0, 0);
    }
    if (t + 1 < NT) {
      __syncthreads();                     // B2: sV free, drains K(t+1) loads
      stage_v(ns_base + (t + 1) * 128);    // latency hides under QK(t+1)
    }
  }
#pragma unroll
  for (int r = 0; r < 4; ++r) {
    float inv = 1.f / onl[r];
    int prow = prow0 + r * 136;
#pragma unroll
    for (int nc = 0; nc < 4; ++nc)
      sP[prow + nc * 16 + l16] = f2b(on[nc][r] * inv);
  }
  __syncthreads();
#pragma unroll
  for (int i = 0; i < 2; ++i) {
    int c = i * 256 + tid;
    int row = c >> 3, cc = c & 7;
    *reinterpret_cast<uint4*>(Ot + (size_t)(nq0 + row) * 768 + hc + cc * 8) =
        *reinterpret_cast<const uint4*>(sP + row * 136 + cc * 8);
  }
}

// ---------------------------------------------------------------------------
extern "C" void kernel_launch(void* const* d_in, const int* in_sizes, int n_in,
                              void* d_out, int out_size, void* d_ws, size_t ws_size,
                              hipStream_t stream) {
  (void)in_sizes; (void)n_in; (void)out_size; (void)ws_size;
  const float* video = (const float*)d_in[0];
  const float* audio = (const float*)d_in[1];
  const float* vn_s = (const float*)d_in[2];
  const float* vn_b = (const float*)d_in[3];
  const float* an_s = (const float*)d_in[4];
  const float* an_b = (const float*)d_in[5];
  const float* vqkv_w = (const float*)d_in[6];
  const float* vqkv_b = (const float*)d_in[7];
  const float* aqkv_w = (const float*)d_in[8];
  const float* aqkv_b = (const float*)d_in[9];
  const float* vproj_w = (const float*)d_in[10];
  const float* vproj_b = (const float*)d_in[11];
  const float* aproj_w = (const float*)d_in[12];
  const float* aproj_b = (const float*)d_in[13];

  float* out_v = (float*)d_out;
  float* out_a = out_v + (size_t)4 * 16 * 768 * 16 * 16;

  char* ws = (char*)d_ws;
  size_t off = 0;
  auto carve = [&](size_t bytes) {
    char* p = ws + off;
    off += (bytes + 255) & ~(size_t)255;
    return p;
  };
  float* part = (float*)carve(2560 * 2 * 4);
  ushort_t* Xv = (ushort_t*)carve((size_t)16384 * 768 * 2);
  ushort_t* Xa = (ushort_t*)carve((size_t)4096 * 768 * 2);
  ushort_t* Wqv = (ushort_t*)carve((size_t)2304 * 768 * 2);
  ushort_t* Wqa = (ushort_t*)carve((size_t)2304 * 768 * 2);
  ushort_t* Wpv = (ushort_t*)carve((size_t)768 * 768 * 2);
  ushort_t* Wpa = (ushort_t*)carve((size_t)768 * 768 * 2);
  ushort_t* Qv = (ushort_t*)carve((size_t)16384 * 768 * 2);
  ushort_t* Kv = (ushort_t*)carve((size_t)16384 * 768 * 2);
  ushort_t* Vv = (ushort_t*)carve((size_t)16384 * 768 * 2);
  ushort_t* Qa = (ushort_t*)carve((size_t)4096 * 768 * 2);
  ushort_t* Ka = (ushort_t*)carve((size_t)4096 * 768 * 2);
  ushort_t* Va = (ushort_t*)carve((size_t)4096 * 768 * 2);
  ushort_t* Ov = Xv;  // alias: X no longer needed after QKV GEMM
  ushort_t* Oa = Xa;

  fused_pre_kernel<<<3584, 256, 0, stream>>>(video, audio, part,
                                             vqkv_w, aqkv_w, vproj_w, aproj_w,
                                             Wqv, Wqa, Wpv, Wpa);
  norm_fused_kernel<<<1920, 256, 0, stream>>>(video, audio, part,
                                              vn_s, vn_b, an_s, an_b, Xv, Xa);
  qkv_fused_kernel<<<2880, 256, 0, stream>>>(Xv, Xa, Wqv, Wqa, vqkv_b, aqkv_b,
                                             Qv, Kv, Vv, Qa, Ka, Va);
  attn_fused_kernel<<<3840, 256, 0, stream>>>(Qv, Ka, Va, Ov, Qa, Kv, Vv, Oa);
  proj_fused_kernel<<<960, 256, 0, stream>>>(Ov, Oa, Wpv, Wpa, vproj_b, aproj_b,
                                             out_v, video, out_a, audio);
}

// Round 12
// 321.851 us; speedup vs baseline: 2.1913x; 1.0095x over previous
//
#include <hip/hip_runtime.h>
#include <hip/hip_bf16.h>

typedef unsigned short ushort_t;
typedef __attribute__((ext_vector_type(8))) short short8;
typedef __attribute__((ext_vector_type(4))) float f32x4;
struct __align__(8) us4 { ushort_t x, y, z, w; };

#define DI __device__ __forceinline__

DI float b2f(unsigned int u16) {
  union { unsigned int i; float f; } v;
  v.i = u16 << 16;
  return v.f;
}
DI ushort_t f2b(float f) {
  union { float f; unsigned int u; } v; v.f = f;
  unsigned int r = v.u + 0x7FFFu + ((v.u >> 16) & 1u);
  return (ushort_t)(r >> 16);
}

// async global->LDS 16B copy: LDS dest is wave-uniform base + lane*16
DI void gl_lds16(const ushort_t* g, ushort_t* l) {
  __builtin_amdgcn_global_load_lds(
      (const __attribute__((address_space(1))) unsigned int*)g,
      (__attribute__((address_space(3))) unsigned int*)l, 16, 0, 0);
}

// ---------------------------------------------------------------------------
// Fused: GroupNorm partial stats (blocks 0..2559) + weight bf16 cvt (2560..3583)
// All loads float4 (16B/lane); wcvt emits ushort4 (8B/lane).
// ---------------------------------------------------------------------------
__global__ __launch_bounds__(256) void fused_pre_kernel(
    const float* __restrict__ video, const float* __restrict__ audio,
    float* __restrict__ part,
    const float* __restrict__ w0, const float* __restrict__ w1,
    const float* __restrict__ w2, const float* __restrict__ w3,
    ushort_t* __restrict__ o0, ushort_t* __restrict__ o1,
    ushort_t* __restrict__ o2, ushort_t* __restrict__ o3) {
  const int bid = blockIdx.x;
  const int tid = threadIdx.x;
  __shared__ float red[8];
  if (bid < 2560) {
    float s = 0.f, ss = 0.f;
    if (bid < 2048) {
      int bg = bid >> 4, f = bid & 15;
      int b = bg >> 5, g = bg & 31;
      // 24ch x 256hw slab is 6144 contiguous floats = 1536 float4
      const float4* base = reinterpret_cast<const float4*>(
          video + ((size_t)((b * 16 + f) * 768 + g * 24)) * 256);
#pragma unroll
      for (int i = 0; i < 6; ++i) {
        float4 v = base[i * 256 + tid];
        s += v.x + v.y + v.z + v.w;
        ss += v.x * v.x + v.y * v.y + v.z * v.z + v.w * v.w;
      }
    } else {
      int a = bid - 2048;
      int bg = a >> 2, p = a & 3;
      int b = bg >> 5, g = bg & 31;
      // 24 rows (stride 1024), 256 floats each: 4 rows/pass x 64 float4
      const float* ab = audio + ((size_t)(b * 768 + g * 24)) * 1024 + p * 256;
#pragma unroll
      for (int i = 0; i < 6; ++i) {
        int row = i * 4 + (tid >> 6);
        float4 v = *reinterpret_cast<const float4*>(ab + (size_t)row * 1024 + (tid & 63) * 4);
        s += v.x + v.y + v.z + v.w;
        ss += v.x * v.x + v.y * v.y + v.z * v.z + v.w * v.w;
      }
    }
    for (int off = 32; off > 0; off >>= 1) { s += __shfl_down(s, off, 64); ss += __shfl_down(ss, off, 64); }
    int wv = tid >> 6, ln = tid & 63;
    if (ln == 0) { red[wv * 2] = s; red[wv * 2 + 1] = ss; }
    __syncthreads();
    if (tid == 0) {
      part[bid * 2] = red[0] + red[2] + red[4] + red[6];
      part[bid * 2 + 1] = red[1] + red[3] + red[5] + red[7];
    }
  } else {
    // weight cvt in float4 -> ushort4 units
    const int n1 = (2304 * 768) / 4, n3 = (768 * 768) / 4;
    const int total = 2 * n1 + 2 * n3;
    int wb = bid - 2560;
    for (int i = wb * 256 + tid; i < total; i += 1024 * 256) {
      const float4* src;
      ushort_t* dst;
      int j;
      if (i < n1) { src = (const float4*)w0; dst = o0; j = i; }
      else if (i < 2 * n1) { src = (const float4*)w1; dst = o1; j = i - n1; }
      else if (i < 2 * n1 + n3) { src = (const float4*)w2; dst = o2; j = i - 2 * n1; }
      else { src = (const float4*)w3; dst = o3; j = i - 2 * n1 - n3; }
      float4 v = src[j];
      us4 o = {f2b(v.x), f2b(v.y), f2b(v.z), f2b(v.w)};
      *reinterpret_cast<us4*>(dst + (size_t)j * 4) = o;
    }
  }
}

// ---------------------------------------------------------------------------
// Fused normalize (gn_final folded in: per-block channel stats from `part`).
// Blocks 0..1535: video -> Xv[n][c]; 1536..1919: audio -> Xa[n][c].
// float4 loads (one wave = one full 1KB row), ushort4 stores (4 ch/lane).
// ---------------------------------------------------------------------------
__global__ __launch_bounds__(256) void norm_fused_kernel(
    const float* __restrict__ video, const float* __restrict__ audio,
    const float* __restrict__ part,
    const float* __restrict__ vsc, const float* __restrict__ vbi,
    const float* __restrict__ asc, const float* __restrict__ abi,
    ushort_t* __restrict__ Xv, ushort_t* __restrict__ Xa) {
  __shared__ float T[32][257];
  __shared__ float shA[32], shB[32];  // per-channel scale/shift: y = A*x + B
  const int bx = blockIdx.x;
  const int tid = threadIdx.x;
  if (bx < 1536) {
    const int bf = bx / 24, ct = bx % 24;
    const int b = bf >> 4, f = bf & 15;
    const int c0 = ct * 32;
    if (tid < 32) {
      int c = c0 + tid, g = c / 24;
      float s = 0.f, ss = 0.f;
#pragma unroll
      for (int i = 0; i < 16; ++i) {
        s += part[((b * 32 + g) * 16 + i) * 2];
        ss += part[((b * 32 + g) * 16 + i) * 2 + 1];
      }
      const float N = 24.f * 4096.f;
      float m = s / N;
      float r = rsqrtf(ss / N - m * m + 1e-5f);
      float A = r * vsc[c];
      shA[tid] = A;
      shB[tid] = vbi[c] - m * A;
    }
    __syncthreads();
    // load+normalize: 32 rows x 64 float4; one wave covers one row per iter
#pragma unroll
    for (int i = 0; i < 8; ++i) {
      int idx = i * 256 + tid;
      int c = idx >> 6, q4 = idx & 63;
      float4 v = *reinterpret_cast<const float4*>(
          video + ((size_t)((b * 16 + f) * 768 + c0 + c)) * 256 + q4 * 4);
      float A = shA[c], B = shB[c];
      float4 o = {A * v.x + B, A * v.y + B, A * v.z + B, A * v.w + B};
      *reinterpret_cast<float4*>(&T[c][q4 * 4]) = o;
    }
    __syncthreads();
    // store token-major: 256 hw x 8 ch-quads; ushort4 per lane
#pragma unroll
    for (int i = 0; i < 8; ++i) {
      int idx = i * 256 + tid;
      int c4 = idx & 7, hw = idx >> 3;
      us4 o = {f2b(T[c4 * 4 + 0][hw]), f2b(T[c4 * 4 + 1][hw]),
               f2b(T[c4 * 4 + 2][hw]), f2b(T[c4 * 4 + 3][hw])};
      *reinterpret_cast<us4*>(Xv + ((size_t)(b * 4096 + f * 256 + hw)) * 768 + c0 + c4 * 4) = o;
    }
  } else {
    const int ax = bx - 1536;
    const int bt = ax / 24, ct = ax % 24;
    const int b = bt >> 2, t0 = (bt & 3) * 256;
    const int c0 = ct * 32;
    if (tid < 32) {
      int c = c0 + tid, g = c / 24;
      float s = 0.f, ss = 0.f;
#pragma unroll
      for (int i = 0; i < 4; ++i) {
        s += part[(2048 + (b * 32 + g) * 4 + i) * 2];
        ss += part[(2048 + (b * 32 + g) * 4 + i) * 2 + 1];
      }
      const float N = 24.f * 1024.f;
      float m = s / N;
      float r = rsqrtf(ss / N - m * m + 1e-5f);
      float A = r * asc[c];
      shA[tid] = A;
      shB[tid] = abi[c] - m * A;
    }
    __syncthreads();
#pragma unroll
    for (int i = 0; i < 8; ++i) {
      int idx = i * 256 + tid;
      int c = idx >> 6, q4 = idx & 63;
      float4 v = *reinterpret_cast<const float4*>(
          audio + ((size_t)(b * 768 + c0 + c)) * 1024 + t0 + q4 * 4);
      float A = shA[c], B = shB[c];
      float4 o = {A * v.x + B, A * v.y + B, A * v.z + B, A * v.w + B};
      *reinterpret_cast<float4*>(&T[c][q4 * 4]) = o;
    }
    __syncthreads();
#pragma unroll
    for (int i = 0; i < 8; ++i) {
      int idx = i * 256 + tid;
      int c4 = idx & 7, tt = idx >> 3;
      us4 o = {f2b(T[c4 * 4 + 0][tt]), f2b(T[c4 * 4 + 1][tt]),
               f2b(T[c4 * 4 + 2][tt]), f2b(T[c4 * 4 + 3][tt])};
      *reinterpret_cast<us4*>(Xa + ((size_t)(b * 1024 + t0 + tt)) * 768 + c0 + c4 * 4) = o;
    }
  }
}

// ---------------------------------------------------------------------------
// Fused QKV GEMM (video blocks 0..2303, audio 2304..2879).
// 128x128 tile, 2-phase dbuf gl_lds16 staging, XOR chunk swizzle both sides,
// segment-local XCD bijective block swizzle.
// Q section pre-scaled by 0.125*log2(e): attention softmax runs in exp2 domain.
// ---------------------------------------------------------------------------
__global__ __launch_bounds__(256) void qkv_fused_kernel(
    const ushort_t* __restrict__ Xv, const ushort_t* __restrict__ Xa,
    const ushort_t* __restrict__ Wqv, const ushort_t* __restrict__ Wqa,
    const float* __restrict__ vqkv_b, const float* __restrict__ aqkv_b,
    ushort_t* __restrict__ Qv, ushort_t* __restrict__ Kv, ushort_t* __restrict__ Vv,
    ushort_t* __restrict__ Qa, ushort_t* __restrict__ Ka, ushort_t* __restrict__ Va) {
  __shared__ ushort_t sm[32768];  // 64 KiB dbuf
  const int bid = blockIdx.x;
  const int tid = threadIdx.x;
  const int lane = tid & 63, wave = tid >> 6;
  const int quad = lane >> 4, l16 = lane & 15;

  const bool isv = bid < 2304;
  const int lb = isv ? bid : bid - 2304;
  const int nwg = isv ? 2304 : 576;
  const ushort_t* A = isv ? Xv : Xa;
  const ushort_t* W = isv ? Wqv : Wqa;
  const float* bias = isv ? vqkv_b : aqkv_b;
  ushort_t* pQ = isv ? Qv : Qa;
  ushort_t* pK = isv ? Kv : Ka;
  ushort_t* pV = isv ? Vv : Va;
  const int M = isv ? 16384 : 4096;

  const int lid = (lb & 7) * (nwg >> 3) + (lb >> 3);
  const int n0 = (lid % 18) * 128, m0 = (lid / 18) * 128;
  const int wm = (wave & 1) * 64, wn = (wave >> 1) * 64;

  const int srow = wave * 32 + (lane >> 3);
  const int sq = ((lane & 7) ^ (lane >> 3)) * 8;
  const ushort_t* gA = A + (size_t)(m0 + srow) * 768 + sq;
  const ushort_t* gB = W + (size_t)(n0 + srow) * 768 + sq;

  f32x4 acc[4][4];
#pragma unroll
  for (int i = 0; i < 4; ++i)
#pragma unroll
    for (int j = 0; j < 4; ++j) acc[i][j] = (f32x4){0.f, 0.f, 0.f, 0.f};

  auto stage = [&](int kc, int cur) {
    ushort_t* lA = sm + cur * 8192 + wave * 2048;
    ushort_t* lB = sm + 16384 + cur * 8192 + wave * 2048;
#pragma unroll
    for (int i = 0; i < 4; ++i) {
      gl_lds16(gA + (size_t)i * 8 * 768 + kc, lA + i * 512);
      gl_lds16(gB + (size_t)i * 8 * 768 + kc, lB + i * 512);
    }
  };

  stage(0, 0);
  __syncthreads();
  int cur = 0;
  for (int t = 0; t < 12; ++t) {
    if (t < 11) stage((t + 1) * 64, cur ^ 1);
    const ushort_t* cA = sm + cur * 8192;
    const ushort_t* cB = sm + 16384 + cur * 8192;
#pragma unroll
    for (int ks = 0; ks < 2; ++ks) {
      short8 av[4], bv[4];
#pragma unroll
      for (int im = 0; im < 4; ++im) {
        int rr = wm + im * 16 + l16;
        av[im] = *reinterpret_cast<const short8*>(
            cA + rr * 64 + (((ks * 4 + quad) ^ (rr & 7)) * 8));
      }
#pragma unroll
      for (int in = 0; in < 4; ++in) {
        int rr = wn + in * 16 + l16;
        bv[in] = *reinterpret_cast<const short8*>(
            cB + rr * 64 + (((ks * 4 + quad) ^ (rr & 7)) * 8));
      }
#pragma unroll
      for (int im = 0; im < 4; ++im)
#pragma unroll
        for (int in = 0; in < 4; ++in)
          acc[im][in] = __builtin_amdgcn_mfma_f32_16x16x32_bf16(av[im], bv[in], acc[im][in], 0, 0, 0);
    }
    __syncthreads();
    cur ^= 1;
  }

  ushort_t* sC = sm;  // epilogue scratch [128][136] bf16
  const int section = n0 / 768;  // 0=Q 1=K 2=V
  const int obase = n0 - section * 768;
  if (section < 2) {
    // fold qk scale AND log2(e) into Q: softmax uses native exp2
    const float qs = (section == 0) ? 0.125f * 1.44269504088896340736f : 1.0f;
#pragma unroll
    for (int in = 0; in < 4; ++in) {
      int ol = wn + in * 16 + l16;
      float bv_ = bias[n0 + ol];
#pragma unroll
      for (int im = 0; im < 4; ++im)
#pragma unroll
        for (int r = 0; r < 4; ++r) {
          int row = wm + im * 16 + quad * 4 + r;
          sC[row * 136 + ol] = f2b((acc[im][in][r] + bv_) * qs);
        }
    }
    __syncthreads();
    ushort_t* dst = (section == 0) ? pQ : pK;
#pragma unroll
    for (int i = 0; i < 8; ++i) {
      int cid = i * 256 + tid;
      int row = cid >> 4, ch = cid & 15;
      *reinterpret_cast<uint4*>(dst + (size_t)(m0 + row) * 768 + obase + ch * 8) =
          *reinterpret_cast<const uint4*>(sC + row * 136 + ch * 8);
    }
  } else {
#pragma unroll
    for (int in = 0; in < 4; ++in) {
      int ol = wn + in * 16 + l16;
      float bv_ = bias[n0 + ol];
#pragma unroll
      for (int im = 0; im < 4; ++im)
#pragma unroll
        for (int r = 0; r < 4; ++r) {
          int mr = wm + im * 16 + quad * 4 + r;
          sC[ol * 136 + mr] = f2b(acc[im][in][r] + bv_);
        }
    }
    __syncthreads();
#pragma unroll
    for (int i = 0; i < 8; ++i) {
      int cid = i * 256 + tid;
      int o = cid >> 4, ch = cid & 15;
      *reinterpret_cast<uint4*>(pV + (size_t)(obase + o) * M + m0 + ch * 8) =
          *reinterpret_cast<const uint4*>(sC + o * 136 + ch * 8);
    }
  }
}

// ---------------------------------------------------------------------------
// Fused proj GEMM + residual (video blocks 0..767, audio 768..959)
// ---------------------------------------------------------------------------
__global__ __launch_bounds__(256) void proj_fused_kernel(
    const ushort_t* __restrict__ Ov, const ushort_t* __restrict__ Oa,
    const ushort_t* __restrict__ Wpv, const ushort_t* __restrict__ Wpa,
    const float* __restrict__ vproj_b, const float* __restrict__ aproj_b,
    float* __restrict__ out_v, const float* __restrict__ video,
    float* __restrict__ out_a, const float* __restrict__ audio) {
  __shared__ ushort_t sm[32768];
  const int bid = blockIdx.x;
  const int tid = threadIdx.x;
  const int lane = tid & 63, wave = tid >> 6;
  const int quad = lane >> 4, l16 = lane & 15;

  const bool isv = bid < 768;
  const int lb = isv ? bid : bid - 768;
  const int nwg = isv ? 768 : 192;
  const ushort_t* A = isv ? Ov : Oa;
  const ushort_t* W = isv ? Wpv : Wpa;
  const float* bias = isv ? vproj_b : aproj_b;
  float* outp = isv ? out_v : out_a;
  const float* resp = isv ? video : audio;

  const int lid = (lb & 7) * (nwg >> 3) + (lb >> 3);
  const int n0 = (lid % 6) * 128, m0 = (lid / 6) * 128;
  const int wm = (wave & 1) * 64, wn = (wave >> 1) * 64;

  const int srow = wave * 32 + (lane >> 3);
  const int sq = ((lane & 7) ^ (lane >> 3)) * 8;
  const ushort_t* gA = A + (size_t)(m0 + srow) * 768 + sq;
  const ushort_t* gB = W + (size_t)(n0 + srow) * 768 + sq;

  f32x4 acc[4][4];
#pragma unroll
  for (int i = 0; i < 4; ++i)
#pragma unroll
    for (int j = 0; j < 4; ++j) acc[i][j] = (f32x4){0.f, 0.f, 0.f, 0.f};

  auto stage = [&](int kc, int cur) {
    ushort_t* lA = sm + cur * 8192 + wave * 2048;
    ushort_t* lB = sm + 16384 + cur * 8192 + wave * 2048;
#pragma unroll
    for (int i = 0; i < 4; ++i) {
      gl_lds16(gA + (size_t)i * 8 * 768 + kc, lA + i * 512);
      gl_lds16(gB + (size_t)i * 8 * 768 + kc, lB + i * 512);
    }
  };

  stage(0, 0);
  __syncthreads();
  int cur = 0;
  for (int t = 0; t < 12; ++t) {
    if (t < 11) stage((t + 1) * 64, cur ^ 1);
    const ushort_t* cA = sm + cur * 8192;
    const ushort_t* cB = sm + 16384 + cur * 8192;
#pragma unroll
    for (int ks = 0; ks < 2; ++ks) {
      short8 av[4], bv[4];
#pragma unroll
      for (int im = 0; im < 4; ++im) {
        int rr = wm + im * 16 + l16;
        av[im] = *reinterpret_cast<const short8*>(
            cA + rr * 64 + (((ks * 4 + quad) ^ (rr & 7)) * 8));
      }
#pragma unroll
      for (int in = 0; in < 4; ++in) {
        int rr = wn + in * 16 + l16;
        bv[in] = *reinterpret_cast<const short8*>(
            cB + rr * 64 + (((ks * 4 + quad) ^ (rr & 7)) * 8));
      }
#pragma unroll
      for (int im = 0; im < 4; ++im)
#pragma unroll
        for (int in = 0; in < 4; ++in)
          acc[im][in] = __builtin_amdgcn_mfma_f32_16x16x32_bf16(av[im], bv[in], acc[im][in], 0, 0, 0);
    }
    __syncthreads();
    cur ^= 1;
  }

  ushort_t* sC = sm;  // [128 o][136] bf16, transposed store
#pragma unroll
  for (int in = 0; in < 4; ++in) {
    int ol = wn + in * 16 + l16;
    float bv_ = bias[n0 + ol];
#pragma unroll
    for (int im = 0; im < 4; ++im)
#pragma unroll
      for (int r = 0; r < 4; ++r) {
        int mr = wm + im * 16 + quad * 4 + r;
        sC[ol * 136 + mr] = f2b(acc[im][in][r] + bv_);
      }
  }
  __syncthreads();
#pragma unroll
  for (int i = 0; i < 16; ++i) {
    int cid = i * 256 + tid;
    int o = cid >> 5, ch = cid & 31;
    uint2 pk = *reinterpret_cast<const uint2*>(sC + o * 136 + ch * 4);
    size_t gidx;
    if (isv) {
      int b = m0 >> 12, f = (m0 >> 8) & 15, hw0 = m0 & 255;
      gidx = ((size_t)((b * 16 + f) * 768 + n0 + o)) * 256 + hw0 + ch * 4;
    } else {
      int b = m0 >> 10, t0 = m0 & 1023;
      gidx = ((size_t)(b * 768 + n0 + o)) * 1024 + t0 + ch * 4;
    }
    float4 rv = *reinterpret_cast<const float4*>(resp + gidx);
    float4 ov;
    ov.x = rv.x + b2f(pk.x & 0xffff);
    ov.y = rv.y + b2f(pk.x >> 16);
    ov.z = rv.z + b2f(pk.y & 0xffff);
    ov.w = rv.w + b2f(pk.y >> 16);
    *reinterpret_cast<float4*>(outp + gidx) = ov;
  }
}

// ---------------------------------------------------------------------------
// Fused MFMA flash attention, 512-thread blocks (128 q-rows, two 64-row
// halves sharing sK/sV). Round-12 fix vs round 11: the Q-staging
// global_load_lds destination is now SYNTACTICALLY wave-uniform (rbase
// hoisted; no lane term in the LDS pointer) -- the lane-dependent-looking
// dest was the only new construct in the build that failed.
// Occupancy 2 blocks x 8 waves = 16 waves/CU. Waves 0-3 own q-rows [0,64)
// with sP0; waves 4-7 own [64,128) with sP1. Per-tile schedule:
//   QK(t)[sK] ; B1 (drains V(t)) ; stage_k(t+1) ; softmax -> sP(half) ;
//   PV(t)[sV,sP] ; B2 (drains K(t+1)) ; stage_v(t+1)
// T5 setprio(1) wraps both MFMA clusters. Segment-local XCD swizzle; heavy
// audio-q (NT=8) blocks dispatch first: bx0 0..383 audio (384=8*48),
// 384..1919 video (1536=8*192). Keeps exp2-domain softmax, ones-MFMA
// row-sum, round-half-up P->bf16, max3 chains.
// ---------------------------------------------------------------------------
__global__ __launch_bounds__(512) void attn_fused_kernel(
    const ushort_t* __restrict__ Qv, const ushort_t* __restrict__ Ka,
    const ushort_t* __restrict__ Va, ushort_t* __restrict__ Ov,
    const ushort_t* __restrict__ Qa, const ushort_t* __restrict__ Kv,
    const ushort_t* __restrict__ Vv, ushort_t* __restrict__ Oa) {
  __shared__ ushort_t sm[33792];       // 67584 B -> 2 blocks/CU (16 waves)
  ushort_t* sK = sm;                   // [128][64] xor8, 16 KB
  ushort_t* sV = sm + 8192;            // [64][128] xor16, 16 KB
  ushort_t* sP = sm + 16384;           // 2 x [64][136] bf16 (one per half)
  const int tid = threadIdx.x;
  const int lane = tid & 63, wave = tid >> 6;   // 8 waves
  const int quad = lane >> 4, l16 = lane & 15;
  const int half = wave >> 2, w4 = wave & 3;
  ushort_t* sPh = sP + half * 8704;    // this wave's P/O buffer
  ushort_t* sQh = sPh;                 // Q alias: consumed to regs pre-softmax

  // Segment-local XCD swizzle; heavy audio-q segment dispatched first.
  const int bx0 = blockIdx.x;
  const bool isv = bx0 >= 384;
  int lb;
  if (isv) {
    int local = bx0 - 384;             // 1536 = 8 * 192
    lb = (local & 7) * 192 + (local >> 3);
  } else {
    int local = bx0;                   // 384 = 8 * 48
    lb = (local & 7) * 48 + (local >> 3);
  }

  const ushort_t* Qt = isv ? Qv : Qa;
  const ushort_t* Kt = isv ? Ka : Kv;
  const ushort_t* Vc = isv ? Va : Vv;
  ushort_t* Ot = isv ? Ov : Oa;
  const int qlog = isv ? 3 : 1;        // q-blocks of 128 rows
  const int NT = isv ? 2 : 8;          // SW/128
  const int QW = isv ? 1024 : 256;
  const int SW = isv ? 256 : 1024;
  const int TQb = isv ? 4096 : 1024;
  const int TSb = isv ? 1024 : 4096;
  const int Ms = isv ? 4096 : 16384;

  const int qt = lb & ((1 << qlog) - 1);
  const int win = (lb >> qlog) & 3;
  const int whb = lb >> (qlog + 2);
  const int h = whb % 12;
  const int batch = whb / 12;
  const int hc = h * 64;
  const int nq0 = batch * TQb + win * QW + qt * 128;
  const int ns_base = batch * TSb + win * SW;

  const int r8 = lane >> 3, c8 = lane & 7;
  const int s8 = (c8 ^ r8) * 8;
  const int r16 = lane >> 4, c16 = lane & 15;

  auto stage_k = [&](int ns0) {       // 128 rows over 8 waves x 2 issues
#pragma unroll
    for (int i = 0; i < 2; ++i) {
      int rbase = wave * 16 + i * 8;  // lane-free LDS base
      gl_lds16(Kt + (size_t)(ns0 + rbase + r8) * 768 + hc + s8, sK + rbase * 64);
    }
  };
  auto stage_v = [&](int ns0) {       // 64 ch over 8 waves x 2 issues
#pragma unroll
    for (int i = 0; i < 2; ++i) {
      int cbase = wave * 8 + i * 4;   // lane-free LDS base
      int ch = cbase + r16;
      int slot = c16 ^ (ch & 15);
      gl_lds16(Vc + (size_t)(hc + ch) * Ms + ns0 + slot * 8, sV + cbase * 128);
    }
  };

  // prologue: Q (128 rows -> sP0/sP1 aliases), K(0), V(0); single drain
#pragma unroll
  for (int i = 0; i < 2; ++i) {
    int rbase = wave * 16 + i * 8;    // multiple of 8; never crosses 64-row half
    gl_lds16(Qt + (size_t)(nq0 + rbase + r8) * 768 + hc + s8,
             sP + (rbase >> 6) * 8704 + (rbase & 63) * 64);  // lane-free dest
  }
  stage_k(ns_base);
  stage_v(ns_base);
  __syncthreads();

  short8 qf[2];
#pragma unroll
  for (int ks = 0; ks < 2; ++ks)
    qf[ks] = *reinterpret_cast<const short8*>(
        sQh + (w4 * 16 + l16) * 64 + (((ks * 4 + quad) ^ (l16 & 7)) * 8));

  const short8 vones = {0x3F80, 0x3F80, 0x3F80, 0x3F80, 0x3F80, 0x3F80, 0x3F80, 0x3F80};

  float mr[4];
  f32x4 on[4], onl;
#pragma unroll
  for (int r = 0; r < 4; ++r) mr[r] = -1e30f;
#pragma unroll
  for (int nc = 0; nc < 4; ++nc) on[nc] = (f32x4){0.f, 0.f, 0.f, 0.f};
  onl = (f32x4){0.f, 0.f, 0.f, 0.f};
  const int prow0 = (w4 * 16 + quad * 4) * 136;

  for (int t = 0; t < NT; ++t) {
    // ---- S = Q K^T (sK tile t; V(t) loads may still be in flight)
    f32x4 sf[8];
#pragma unroll
    for (int nt = 0; nt < 8; ++nt) sf[nt] = (f32x4){0.f, 0.f, 0.f, 0.f};
    __builtin_amdgcn_s_setprio(1);
#pragma unroll
    for (int ks = 0; ks < 2; ++ks) {
#pragma unroll
      for (int nt = 0; nt < 8; ++nt) {
        short8 kf = *reinterpret_cast<const short8*>(
            sK + (nt * 16 + l16) * 64 + (((ks * 4 + quad) ^ (l16 & 7)) * 8));
        sf[nt] = __builtin_amdgcn_mfma_f32_16x16x32_bf16(qf[ks], kf, sf[nt], 0, 0, 0);
      }
    }
    __builtin_amdgcn_s_setprio(0);
    __syncthreads();  // B1: all waves done with sK; drains V(t) loads
    if (t + 1 < NT) stage_k(ns_base + (t + 1) * 128);  // overlaps softmax+PV
    // ---- online softmax in exp2 domain; row-sum deferred to ones-MFMA
#pragma unroll
    for (int r = 0; r < 4; ++r) {
      float m_ = fmaxf(fmaxf(sf[0][r], sf[1][r]), sf[2][r]);
      m_ = fmaxf(fmaxf(m_, sf[3][r]), sf[4][r]);
      m_ = fmaxf(fmaxf(m_, sf[5][r]), sf[6][r]);
      m_ = fmaxf(m_, sf[7][r]);
#pragma unroll
      for (int off = 1; off < 16; off <<= 1) m_ = fmaxf(m_, __shfl_xor(m_, off));
      float mnew = fmaxf(mr[r], m_);
      float al = __builtin_amdgcn_exp2f(mr[r] - mnew);
      mr[r] = mnew;
      int prow = prow0 + r * 136;
#pragma unroll
      for (int nt = 0; nt < 8; ++nt) {
        float p = __builtin_amdgcn_exp2f(sf[nt][r] - mnew);
        sPh[prow + nt * 16 + l16] = (ushort_t)((__float_as_uint(p) + 0x8000u) >> 16);
      }
#pragma unroll
      for (int nc = 0; nc < 4; ++nc) on[nc][r] *= al;
      onl[r] *= al;
    }
    // ---- O += P V ; l += P 1 (ones-MFMA row-sum)
    __builtin_amdgcn_s_setprio(1);
#pragma unroll
    for (int ks = 0; ks < 4; ++ks) {
      short8 pf = *reinterpret_cast<const short8*>(sPh + (w4 * 16 + l16) * 136 + ks * 32 + quad * 8);
#pragma unroll
      for (int nc = 0; nc < 4; ++nc) {
        short8 vf = *reinterpret_cast<const short8*>(
            sV + (nc * 16 + l16) * 128 + (((ks * 4 + quad) ^ l16) * 8));
        on[nc] = __builtin_amdgcn_mfma_f32_16x16x32_bf16(pf, vf, on[nc], 0, 0, 0);
      }
      onl = __builtin_amdgcn_mfma_f32_16x16x32_bf16(pf, vones, onl, 0, 0, 0);
    }
    __builtin_amdgcn_s_setprio(0);
    if (t + 1 < NT) {
      __syncthreads();                     // B2: sV free, drains K(t+1) loads
      stage_v(ns_base + (t + 1) * 128);    // latency hides under QK(t+1)
    }
  }
#pragma unroll
  for (int r = 0; r < 4; ++r) {
    float inv = 1.f / onl[r];
    int prow = prow0 + r * 136;
#pragma unroll
    for (int nc = 0; nc < 4; ++nc)
      sPh[prow + nc * 16 + l16] = f2b(on[nc][r] * inv);
  }
  __syncthreads();
#pragma unroll
  for (int i = 0; i < 2; ++i) {
    int c = i * 512 + tid;
    int row = c >> 3, cc = c & 7;   // 128 rows x 8 chunks
    *reinterpret_cast<uint4*>(Ot + (size_t)(nq0 + row) * 768 + hc + cc * 8) =
        *reinterpret_cast<const uint4*>(sP + (row >> 6) * 8704 + (row & 63) * 136 + cc * 8);
  }
}

// ---------------------------------------------------------------------------
extern "C" void kernel_launch(void* const* d_in, const int* in_sizes, int n_in,
                              void* d_out, int out_size, void* d_ws, size_t ws_size,
                              hipStream_t stream) {
  (void)in_sizes; (void)n_in; (void)out_size; (void)ws_size;
  const float* video = (const float*)d_in[0];
  const float* audio = (const float*)d_in[1];
  const float* vn_s = (const float*)d_in[2];
  const float* vn_b = (const float*)d_in[3];
  const float* an_s = (const float*)d_in[4];
  const float* an_b = (const float*)d_in[5];
  const float* vqkv_w = (const float*)d_in[6];
  const float* vqkv_b = (const float*)d_in[7];
  const float* aqkv_w = (const float*)d_in[8];
  const float* aqkv_b = (const float*)d_in[9];
  const float* vproj_w = (const float*)d_in[10];
  const float* vproj_b = (const float*)d_in[11];
  const float* aproj_w = (const float*)d_in[12];
  const float* aproj_b = (const float*)d_in[13];

  float* out_v = (float*)d_out;
  float* out_a = out_v + (size_t)4 * 16 * 768 * 16 * 16;

  char* ws = (char*)d_ws;
  size_t off = 0;
  auto carve = [&](size_t bytes) {
    char* p = ws + off;
    off += (bytes + 255) & ~(size_t)255;
    return p;
  };
  float* part = (float*)carve(2560 * 2 * 4);
  ushort_t* Xv = (ushort_t*)carve((size_t)16384 * 768 * 2);
  ushort_t* Xa = (ushort_t*)carve((size_t)4096 * 768 * 2);
  ushort_t* Wqv = (ushort_t*)carve((size_t)2304 * 768 * 2);
  ushort_t* Wqa = (ushort_t*)carve((size_t)2304 * 768 * 2);
  ushort_t* Wpv = (ushort_t*)carve((size_t)768 * 768 * 2);
  ushort_t* Wpa = (ushort_t*)carve((size_t)768 * 768 * 2);
  ushort_t* Qv = (ushort_t*)carve((size_t)16384 * 768 * 2);
  ushort_t* Kv = (ushort_t*)carve((size_t)16384 * 768 * 2);
  ushort_t* Vv = (ushort_t*)carve((size_t)16384 * 768 * 2);
  ushort_t* Qa = (ushort_t*)carve((size_t)4096 * 768 * 2);
  ushort_t* Ka = (ushort_t*)carve((size_t)4096 * 768 * 2);
  ushort_t* Va = (ushort_t*)carve((size_t)4096 * 768 * 2);
  ushort_t* Ov = Xv;  // alias: X no longer needed after QKV GEMM
  ushort_t* Oa = Xa;

  fused_pre_kernel<<<3584, 256, 0, stream>>>(video, audio, part,
                                             vqkv_w, aqkv_w, vproj_w, aproj_w,
                                             Wqv, Wqa, Wpv, Wpa);
  norm_fused_kernel<<<1920, 256, 0, stream>>>(video, audio, part,
                                              vn_s, vn_b, an_s, an_b, Xv, Xa);
  qkv_fused_kernel<<<2880, 256, 0, stream>>>(Xv, Xa, Wqv, Wqa, vqkv_b, aqkv_b,
                                             Qv, Kv, Vv, Qa, Ka, Va);
  attn_fused_kernel<<<1920, 512, 0, stream>>>(Qv, Ka, Va, Ov, Qa, Kv, Vv, Oa);
  proj_fused_kernel<<<960, 256, 0, stream>>>(Ov, Oa, Wpv, Wpa, vproj_b, aproj_b,
                                             out_v, video, out_a, audio);
}